// Round 2
// baseline (761.706 us; speedup 1.0000x reference)
//
#include <hip/hip_runtime.h>
#include <math.h>

#define B_    32
#define T_    2048
#define T2_   1024
#define C_    64
#define FI_   8
#define FO_   32
#define K_    2048   // C_*FO_
#define H_    128

// workspace offsets (in floats)
#define OFF_XC   ((size_t)0)          // 32*1024*64*32  = 67,108,864
#define OFF_WEFF ((size_t)67108864)   // 32*2048*128    =  8,388,608
#define OFF_XSP  ((size_t)75497472)   // 32*32*2048     =  2,097,152
#define OFF_A    ((size_t)77594624)   // 32*64*64       =    131,072
#define OFF_XM   ((size_t)77725696)   // 32*1024*128    =  4,194,304
#define OFF_FS   ((size_t)81920000)   // 32*128         =      4,096

// ---------------------------------------------------------------------------
// K1: conv(5x1, stride 2, SAME) + bias + relu + LayerNorm(32) -> Xc
//     also: per-block partial sums over t2 of post-LN Xc -> xsp[b][blk][c][f]
// grid (32 t2-tiles, 32 b), block 256 = (c:64, tt:4); thread does 4 pairs of t2
// ---------------------------------------------------------------------------
__global__ __launch_bounds__(256) void k1_conv_ln(
    const float* __restrict__ X, const float* __restrict__ Wc,
    const float* __restrict__ bc, const float* __restrict__ g1,
    const float* __restrict__ be1, float* __restrict__ Xc,
    float* __restrict__ xsp)
{
  __shared__ float xacc[4 * 64 * 32];
  const int tid = threadIdx.x;
  const int c  = tid & 63;
  const int tt = tid >> 6;
  const int b  = blockIdx.y;
  const int t2base = blockIdx.x * 32;

  float sacc[32];
#pragma unroll
  for (int j = 0; j < 32; ++j) sacc[j] = 0.f;

#pragma unroll 1
  for (int pair = 0; pair < 4; ++pair) {
    const int t2a = t2base + tt * 2 + 8 * pair;   // and t2a+1
    float acc0[32], acc1[32];
#pragma unroll
    for (int j = 0; j < 32; ++j) { float v = bc[j]; acc0[j] = v; acc1[j] = v; }

#pragma unroll
    for (int kt = 0; kt < 5; ++kt) {
      const int ta = 2 * t2a + kt - 1;
      const int tb = ta + 2;
      float4 a0 = make_float4(0.f,0.f,0.f,0.f), a1 = a0, c0 = a0, c1 = a0;
      if (ta >= 0 && ta < T_) {
        const float* p = X + (((size_t)b * T_ + ta) * C_ + c) * FI_;
        a0 = *(const float4*)p; a1 = *(const float4*)(p + 4);
      }
      if (tb >= 0 && tb < T_) {
        const float* p = X + (((size_t)b * T_ + tb) * C_ + c) * FI_;
        c0 = *(const float4*)p; c1 = *(const float4*)(p + 4);
      }
      float va[8] = {a0.x,a0.y,a0.z,a0.w,a1.x,a1.y,a1.z,a1.w};
      float vb[8] = {c0.x,c0.y,c0.z,c0.w,c1.x,c1.y,c1.z,c1.w};
#pragma unroll
      for (int fi = 0; fi < 8; ++fi) {
#pragma unroll
        for (int j4 = 0; j4 < 8; ++j4) {
          const float4 w4 = *(const float4*)(Wc + ((kt * 8 + fi) * 32 + j4 * 4));
          acc0[j4*4+0] = fmaf(va[fi], w4.x, acc0[j4*4+0]);
          acc0[j4*4+1] = fmaf(va[fi], w4.y, acc0[j4*4+1]);
          acc0[j4*4+2] = fmaf(va[fi], w4.z, acc0[j4*4+2]);
          acc0[j4*4+3] = fmaf(va[fi], w4.w, acc0[j4*4+3]);
          acc1[j4*4+0] = fmaf(vb[fi], w4.x, acc1[j4*4+0]);
          acc1[j4*4+1] = fmaf(vb[fi], w4.y, acc1[j4*4+1]);
          acc1[j4*4+2] = fmaf(vb[fi], w4.z, acc1[j4*4+2]);
          acc1[j4*4+3] = fmaf(vb[fi], w4.w, acc1[j4*4+3]);
        }
      }
    }

    // relu + LN over 32 features, for both t2
#pragma unroll
    for (int which = 0; which < 2; ++which) {
      float* a = which ? acc1 : acc0;
      const int t2 = t2a + which;
      float mu = 0.f;
#pragma unroll
      for (int j = 0; j < 32; ++j) { a[j] = fmaxf(a[j], 0.f); mu += a[j]; }
      mu *= (1.f / 32.f);
      float var = 0.f;
#pragma unroll
      for (int j = 0; j < 32; ++j) { float d = a[j] - mu; var += d * d; }
      var *= (1.f / 32.f);
      const float rs = rsqrtf(var + 1e-6f);
      float* op = Xc + (((size_t)b * T2_ + t2) * C_ + c) * FO_;
      float y[32];
#pragma unroll
      for (int j = 0; j < 32; ++j) {
        y[j] = (a[j] - mu) * rs * g1[j] + be1[j];
        sacc[j] += y[j];
      }
#pragma unroll
      for (int j = 0; j < 32; j += 4)
        *(float4*)(op + j) = make_float4(y[j], y[j+1], y[j+2], y[j+3]);
    }
  }

  // per-(tt,c) partials -> LDS (once), reduce over tt, write global partial
  {
    float* xa = xacc + tt * 2048 + c * 32;
#pragma unroll
    for (int j = 0; j < 32; j += 4)
      *(float4*)(xa + j) = make_float4(sacc[j], sacc[j+1], sacc[j+2], sacc[j+3]);
  }
  __syncthreads();
  for (int idx = tid; idx < 2048; idx += 256) {
    float s = xacc[idx] + xacc[2048 + idx] + xacc[4096 + idx] + xacc[6144 + idx];
    xsp[((size_t)b * 32 + blockIdx.x) * 2048 + idx] = s;
  }
}

// ---------------------------------------------------------------------------
// K2: reduce x_spat partials, compute q,k, adj=softmax(qk^T/sqrt(32)),
//     ca=sigmoid(mean @ ca_w + ca_b); write A'[b,c,d] = ca[c]*adj[c,d] + I
// grid 32 (one block per b), block 256
// ---------------------------------------------------------------------------
__global__ __launch_bounds__(256) void k2_graph(
    const float* __restrict__ xsp, const float* __restrict__ qw,
    const float* __restrict__ qb, const float* __restrict__ kw,
    const float* __restrict__ kb, const float* __restrict__ caw,
    const float* __restrict__ cab, float* __restrict__ Aout)
{
  __shared__ float xs[64 * 32];
  __shared__ float qs[64][32];
  __shared__ float ks[64][32];
  __shared__ float sc[64][64];
  __shared__ float cain[64];
  __shared__ float cav[64];
  const int tid = threadIdx.x;
  const int b = blockIdx.x;

  for (int idx = tid; idx < 2048; idx += 256) {
    float s = 0.f;
    for (int p = 0; p < 32; ++p) s += xsp[((size_t)b * 32 + p) * 2048 + idx];
    xs[idx] = s * (1.f / (float)T2_);
  }
  __syncthreads();

  if (tid < 64) {
    float s = 0.f;
#pragma unroll
    for (int f = 0; f < 32; ++f) s += xs[tid * 32 + f];
    cain[tid] = s * (1.f / 32.f);
  }
  // q, k : (64x32) @ (32x32) + b
  {
    const int cc = tid >> 2, part = tid & 3;
    float aq[8], ak[8];
#pragma unroll
    for (int j = 0; j < 8; ++j) { aq[j] = qb[part*8+j]; ak[j] = kb[part*8+j]; }
    for (int f = 0; f < 32; ++f) {
      const float xv = xs[cc * 32 + f];
#pragma unroll
      for (int j = 0; j < 8; ++j) {
        aq[j] = fmaf(xv, qw[f * 32 + part*8+j], aq[j]);
        ak[j] = fmaf(xv, kw[f * 32 + part*8+j], ak[j]);
      }
    }
#pragma unroll
    for (int j = 0; j < 8; ++j) { qs[cc][part*8+j] = aq[j]; ks[cc][part*8+j] = ak[j]; }
  }
  __syncthreads();
  // scores
  {
    const int cc = tid >> 2, part = tid & 3;
    for (int dd = part * 16; dd < part * 16 + 16; ++dd) {
      float s = 0.f;
#pragma unroll
      for (int e = 0; e < 32; ++e) s = fmaf(qs[cc][e], ks[dd][e], s);
      sc[cc][dd] = s * 0.1767766953f;   // 1/sqrt(32)
    }
  }
  __syncthreads();
  if (tid < 64) {
    const int cc = tid;
    float m = -1e30f;
    for (int d = 0; d < 64; ++d) m = fmaxf(m, sc[cc][d]);
    float sum = 0.f;
    for (int d = 0; d < 64; ++d) { float e = expf(sc[cc][d] - m); sc[cc][d] = e; sum += e; }
    const float inv = 1.f / sum;
    for (int d = 0; d < 64; ++d) sc[cc][d] *= inv;
    float a = cab[cc];
    for (int d = 0; d < 64; ++d) a = fmaf(cain[d], caw[d * 64 + cc], a);
    cav[cc] = 1.f / (1.f + expf(-a));
  }
  __syncthreads();
  for (int idx = tid; idx < 4096; idx += 256) {
    const int cc = idx >> 6, dd = idx & 63;
    Aout[(size_t)b * 4096 + idx] = cav[cc] * sc[cc][dd] + (cc == dd ? 1.f : 0.f);
  }
}

// ---------------------------------------------------------------------------
// K3: W_eff[b] = A'[b]^T @ mix_w  viewed as (64 x 4096) matrices (K=64)
// grid 512 = 32 b x 16 fh-tiles(256); block 256; thread-tile 8d x 8fh
// ---------------------------------------------------------------------------
__global__ __launch_bounds__(256) void k3_weff(
    const float* __restrict__ Aout, const float* __restrict__ mixw,
    float* __restrict__ Weff)
{
  const int tid = threadIdx.x;
  const int b  = blockIdx.x >> 4;
  const int ft = blockIdx.x & 15;
  const int dq = tid >> 5, fq = tid & 31;
  const int d0 = dq * 8;
  const int n0 = ft * 256 + fq * 8;
  float acc[8][8];
#pragma unroll
  for (int i = 0; i < 8; ++i)
#pragma unroll
    for (int j = 0; j < 8; ++j) acc[i][j] = 0.f;

  const float* Ab = Aout + (size_t)b * 4096;
  for (int cc = 0; cc < 64; ++cc) {
    float a[8], m[8];
    *(float4*)&a[0] = *(const float4*)(Ab + cc * 64 + d0);
    *(float4*)&a[4] = *(const float4*)(Ab + cc * 64 + d0 + 4);
    const float* mp = mixw + (size_t)cc * 4096 + n0;
    *(float4*)&m[0] = *(const float4*)mp;
    *(float4*)&m[4] = *(const float4*)(mp + 4);
#pragma unroll
    for (int i = 0; i < 8; ++i)
#pragma unroll
      for (int j = 0; j < 8; ++j) acc[i][j] = fmaf(a[i], m[j], acc[i][j]);
  }
#pragma unroll
  for (int i = 0; i < 8; ++i) {
    float* op = Weff + (size_t)b * (K_ * H_) + (size_t)(d0 + i) * 4096 + n0;
    *(float4*)op       = make_float4(acc[i][0], acc[i][1], acc[i][2], acc[i][3]);
    *(float4*)(op + 4) = make_float4(acc[i][4], acc[i][5], acc[i][6], acc[i][7]);
  }
}

// ---------------------------------------------------------------------------
// K4: per-b GEMM  Xm = LN2(relu(Xc[b](1024x2048) @ W_eff[b](2048x128) + mix_b))
// grid 512 = 32 b x 16 m-tiles(64); block 128; thread-tile 8m x 8n; BK=32
// A staged transposed As[k][m] (pad 68), B staged swizzled Bs[k][phys(n)].
// Physical swizzled extent for n: max pn_w = 31*4 + 12 + 3 = 139 -> row 140.
// (Round-1 bug: row was 136 -> writes for n=124..127 clobbered n=0..3 of the
//  next k-row; h in {0..3,124..127} of Xm were wrong -> 3.1e-2 logit error.)
// ---------------------------------------------------------------------------
#define BK4 32
__global__ __launch_bounds__(128) void k4_gemm(
    const float* __restrict__ Xc, const float* __restrict__ Weff,
    const float* __restrict__ mixb, const float* __restrict__ g2,
    const float* __restrict__ be2, float* __restrict__ Xm)
{
  __shared__ float As[BK4][68];
  __shared__ float Bs[BK4][140];
  const int tid = threadIdx.x;
  const int b  = blockIdx.x >> 4;
  const int mt = blockIdx.x & 15;
  const int row0 = mt * 64;
  const int mq = tid >> 4;        // 0..7 -> m0 = mq*8
  const int nq = tid & 15;        // 0..15 -> n0 = nq*8
  float acc[8][8];
#pragma unroll
  for (int i = 0; i < 8; ++i)
#pragma unroll
    for (int j = 0; j < 8; ++j) acc[i][j] = 0.f;

  const float* Ab = Xc + ((size_t)b * T2_ + row0) * K_;
  const float* Bb = Weff + (size_t)b * (K_ * H_);

  for (int k0 = 0; k0 < K_; k0 += BK4) {
    // stage A (64 x 32), transposed
#pragma unroll
    for (int l = 0; l < 4; ++l) {
      const int ii = tid + 128 * l;       // 0..511
      const int m = ii >> 3, k4 = ii & 7;
      float4 v = *(const float4*)(Ab + (size_t)m * K_ + k0 + k4 * 4);
      As[k4*4+0][m] = v.x; As[k4*4+1][m] = v.y;
      As[k4*4+2][m] = v.z; As[k4*4+3][m] = v.w;
    }
    // stage B (32 x 128), swizzled
#pragma unroll
    for (int l = 0; l < 8; ++l) {
      const int ii = tid + 128 * l;       // 0..1023
      const int k = ii >> 5, n4 = ii & 31;
      float4 v = *(const float4*)(Bb + (size_t)(k0 + k) * H_ + n4 * 4);
      const int pn = n4 * 4 + ((n4 >> 3) << 2);   // max 136..139 -> row 140
      *(float4*)&Bs[k][pn] = v;
    }
    __syncthreads();
    const int pn = nq * 8 + ((nq >> 2) << 2);
#pragma unroll 4
    for (int k = 0; k < BK4; ++k) {
      float a[8], w[8];
      *(float4*)&a[0] = *(const float4*)&As[k][mq * 8];
      *(float4*)&a[4] = *(const float4*)&As[k][mq * 8 + 4];
      *(float4*)&w[0] = *(const float4*)&Bs[k][pn];
      *(float4*)&w[4] = *(const float4*)&Bs[k][pn + 4];
#pragma unroll
      for (int i = 0; i < 8; ++i)
#pragma unroll
        for (int j = 0; j < 8; ++j)
          acc[i][j] = fmaf(a[i], w[j], acc[i][j]);
    }
    __syncthreads();
  }

  // epilogue: +bias, relu, LN over 128 (16 nq-lanes share a row -> shfl_xor)
  float bias[8], gg[8], bb2[8];
#pragma unroll
  for (int j = 0; j < 8; ++j) {
    bias[j] = mixb[nq*8+j]; gg[j] = g2[nq*8+j]; bb2[j] = be2[nq*8+j];
  }
#pragma unroll
  for (int i = 0; i < 8; ++i) {
    float s1 = 0.f, s2 = 0.f;
#pragma unroll
    for (int j = 0; j < 8; ++j) {
      float v = fmaxf(acc[i][j] + bias[j], 0.f);
      acc[i][j] = v; s1 += v; s2 = fmaf(v, v, s2);
    }
#pragma unroll
    for (int off = 1; off < 16; off <<= 1) {
      s1 += __shfl_xor(s1, off, 64);
      s2 += __shfl_xor(s2, off, 64);
    }
    const float mu = s1 * (1.f / 128.f);
    const float var = s2 * (1.f / 128.f) - mu * mu;
    const float rs = rsqrtf(var + 1e-6f);
    float* op = Xm + ((size_t)b * T2_ + row0 + mq * 8 + i) * H_ + nq * 8;
    float o[8];
#pragma unroll
    for (int j = 0; j < 8; ++j) o[j] = (acc[i][j] - mu) * rs * gg[j] + bb2[j];
    *(float4*)op       = make_float4(o[0], o[1], o[2], o[3]);
    *(float4*)(op + 4) = make_float4(o[4], o[5], o[6], o[7]);
  }
}

// ---------------------------------------------------------------------------
// K5: LIF scan over t (sequential), 4096 independent (b,h) chains
// ---------------------------------------------------------------------------
__global__ __launch_bounds__(256) void k5_lif(
    const float* __restrict__ Xm, const float* __restrict__ dl,
    float* __restrict__ fs)
{
  const int tid = threadIdx.x;
  const int b = blockIdx.x * 2 + (tid >> 7);
  const int h = tid & 127;
  const float decay = 1.f / (1.f + expf(-dl[h]));
  float mem = 0.f, cnt = 0.f;
  const float* p = Xm + (size_t)b * T2_ * H_ + h;
#pragma unroll 16
  for (int t = 0; t < T2_; ++t) {
    const float x = p[(size_t)t * H_];
    mem = fmaf(mem, decay, x);
    const float sp = ((mem - 0.5f) > 0.f) ? 1.f : 0.f;   // match ref exactly
    cnt += sp;
    mem -= 0.5f * sp;
  }
  fs[b * H_ + h] = cnt;
}

// ---------------------------------------------------------------------------
// K6: feat = relu(mean_spk @ fc_w + fc_b); logits = feat @ out_w + out_b;
//     plus global spike mean. Single block.
// ---------------------------------------------------------------------------
__global__ __launch_bounds__(256) void k6_head(
    const float* __restrict__ fs, const float* __restrict__ fcw,
    const float* __restrict__ fcb, const float* __restrict__ ow,
    const float* __restrict__ ob, float* __restrict__ out)
{
  __shared__ float f[32 * 128];
  __shared__ float fr[32 * 128];
  __shared__ float red[256];
  const int tid = threadIdx.x;
  float tot = 0.f;
  for (int idx = tid; idx < 4096; idx += 256) {
    const float v = fs[idx];
    f[idx] = v * (1.f / (float)T2_);
    tot += v;
  }
  red[tid] = tot;
  __syncthreads();
  for (int s = 128; s > 0; s >>= 1) {
    if (tid < s) red[tid] += red[tid + s];
    __syncthreads();
  }
  {
    const int bb = tid >> 3, og = tid & 7;   // 16 outputs each
    float a[16];
#pragma unroll
    for (int j = 0; j < 16; ++j) a[j] = fcb[og * 16 + j];
    for (int hh = 0; hh < 128; ++hh) {
      const float fv = f[bb * 128 + hh];
#pragma unroll
      for (int j = 0; j < 16; ++j)
        a[j] = fmaf(fv, fcw[hh * 128 + og * 16 + j], a[j]);
    }
#pragma unroll
    for (int j = 0; j < 16; ++j) fr[bb * 128 + og * 16 + j] = fmaxf(a[j], 0.f);
  }
  __syncthreads();
  if (tid < 128) {
    const int bb = tid >> 2, cls = tid & 3;
    float a = ob[cls];
    for (int o = 0; o < 128; ++o) a = fmaf(fr[bb * 128 + o], ow[o * 4 + cls], a);
    out[bb * 4 + cls] = a;
  }
  if (tid == 0) out[128] = red[0] * (1.f / (4096.f * 1024.f));
}

// ---------------------------------------------------------------------------
extern "C" void kernel_launch(void* const* d_in, const int* in_sizes, int n_in,
                              void* d_out, int out_size, void* d_ws, size_t ws_size,
                              hipStream_t stream) {
  const float* X     = (const float*)d_in[0];
  const float* convw = (const float*)d_in[1];
  const float* convb = (const float*)d_in[2];
  const float* ln1s  = (const float*)d_in[3];
  const float* ln1b  = (const float*)d_in[4];
  const float* qw    = (const float*)d_in[5];
  const float* qb    = (const float*)d_in[6];
  const float* kw    = (const float*)d_in[7];
  const float* kb    = (const float*)d_in[8];
  const float* caw   = (const float*)d_in[9];
  const float* cab   = (const float*)d_in[10];
  const float* mixw  = (const float*)d_in[11];
  const float* mixb  = (const float*)d_in[12];
  const float* ln2s  = (const float*)d_in[13];
  const float* ln2b  = (const float*)d_in[14];
  const float* dl    = (const float*)d_in[15];
  const float* fcw   = (const float*)d_in[16];
  const float* fcb   = (const float*)d_in[17];
  const float* outw  = (const float*)d_in[18];
  const float* outb  = (const float*)d_in[19];

  float* ws   = (float*)d_ws;
  float* Xc   = ws + OFF_XC;
  float* Weff = ws + OFF_WEFF;
  float* xsp  = ws + OFF_XSP;
  float* Aou  = ws + OFF_A;
  float* Xm   = ws + OFF_XM;
  float* fs   = ws + OFF_FS;

  dim3 g1(32, 32);
  k1_conv_ln<<<g1, 256, 0, stream>>>(X, convw, convb, ln1s, ln1b, Xc, xsp);
  k2_graph<<<32, 256, 0, stream>>>(xsp, qw, qb, kw, kb, caw, cab, Aou);
  k3_weff<<<512, 256, 0, stream>>>(Aou, mixw, Weff);
  k4_gemm<<<512, 128, 0, stream>>>(Xc, Weff, mixb, ln2s, ln2b, Xm);
  k5_lif<<<16, 256, 0, stream>>>(Xm, dl, fs);
  k6_head<<<1, 256, 0, stream>>>(fs, fcw, fcb, outw, outb, (float*)d_out);
}

// Round 3
// 504.373 us; speedup vs baseline: 1.5102x; 1.5102x over previous
//
#include <hip/hip_runtime.h>
#include <math.h>

#define B_    32
#define T_    2048
#define T2_   1024
#define C_    64
#define FI_   8
#define FO_   32
#define K_    2048   // C_*CONV_F
#define H_    128

typedef unsigned short u16;
typedef short bf16x8 __attribute__((ext_vector_type(8)));
typedef float f32x4 __attribute__((ext_vector_type(4)));

// workspace offsets (in FLOAT units); total 81,920,000 floats = same footprint
// as the round-2 kernel that passed (so ws_size is known sufficient).
#define OFF_XCH  ((size_t)0)          // bf16 hi Xc: 67,108,864 u16 = 33,554,432 f
#define OFF_XCL  ((size_t)33554432)   // bf16 lo Xc
#define OFF_WTH  ((size_t)67108864)   // bf16 hi Weff_T: 8,388,608 u16
#define OFF_WTL  ((size_t)71303168)
#define OFF_XSP  ((size_t)75497472)   // 32*32*2048 f32
#define OFF_A    ((size_t)77594624)   // 32*64*64 f32 (A'); reused later for fs
#define OFF_XM   ((size_t)77725696)   // 32*1024*128 f32

// ---- bf16 split helpers (RTNE) -------------------------------------------
__device__ __forceinline__ float bft(float x) {  // value of bf16-rounded x
  unsigned u = __float_as_uint(x);
  u = (u + 0x7fffu + ((u >> 16) & 1u)) & 0xffff0000u;
  return __uint_as_float(u);
}
__device__ __forceinline__ unsigned bfpack(float a, float b) { // round both
  unsigned ua = __float_as_uint(a); ua = (ua + 0x7fffu + ((ua >> 16) & 1u)) >> 16;
  unsigned ub = __float_as_uint(b); ub = (ub + 0x7fffu + ((ub >> 16) & 1u)) & 0xffff0000u;
  return ua | ub;
}

// async global->LDS, 16B per lane; LDS dest must be wave-uniform base
__device__ __forceinline__ void glds16(const u16* g, u16* l) {
  auto gp = reinterpret_cast<const __attribute__((address_space(1))) unsigned int*>(
      reinterpret_cast<uintptr_t>(g));
  auto lp = reinterpret_cast<__attribute__((address_space(3))) unsigned int*>(
      reinterpret_cast<uintptr_t>(l));
  __builtin_amdgcn_global_load_lds(gp, lp, 16, 0, 0);
}

// ---------------------------------------------------------------------------
// K1: conv(5x1,s2,SAME)+bias+relu+LN(32) -> Xc as bf16 hi/lo, layout
// [b][t2][c][32f] with 16B f-chunks stored at position g^(t2&3) (bank-swizzle
// pre-baked so k4's global_load_lds staging is linear).  Also xsp partials.
// ---------------------------------------------------------------------------
__global__ __launch_bounds__(256) void k1_conv_ln(
    const float* __restrict__ X, const float* __restrict__ Wc,
    const float* __restrict__ bc, const float* __restrict__ g1,
    const float* __restrict__ be1, u16* __restrict__ Xch,
    u16* __restrict__ Xcl, float* __restrict__ xsp)
{
  __shared__ float xacc[4 * 64 * 32];
  const int tid = threadIdx.x;
  const int c  = tid & 63;
  const int tt = tid >> 6;
  const int b  = blockIdx.y;
  const int t2base = blockIdx.x * 32;

  float sacc[32];
#pragma unroll
  for (int j = 0; j < 32; ++j) sacc[j] = 0.f;

#pragma unroll 1
  for (int pair = 0; pair < 4; ++pair) {
    const int t2a = t2base + tt * 2 + 8 * pair;   // and t2a+1
    float acc0[32], acc1[32];
#pragma unroll
    for (int j = 0; j < 32; ++j) { float v = bc[j]; acc0[j] = v; acc1[j] = v; }

#pragma unroll
    for (int kt = 0; kt < 5; ++kt) {
      const int ta = 2 * t2a + kt - 1;
      const int tb = ta + 2;
      float4 a0 = make_float4(0.f,0.f,0.f,0.f), a1 = a0, c0 = a0, c1 = a0;
      if (ta >= 0 && ta < T_) {
        const float* p = X + (((size_t)b * T_ + ta) * C_ + c) * FI_;
        a0 = *(const float4*)p; a1 = *(const float4*)(p + 4);
      }
      if (tb >= 0 && tb < T_) {
        const float* p = X + (((size_t)b * T_ + tb) * C_ + c) * FI_;
        c0 = *(const float4*)p; c1 = *(const float4*)(p + 4);
      }
      float va[8] = {a0.x,a0.y,a0.z,a0.w,a1.x,a1.y,a1.z,a1.w};
      float vb[8] = {c0.x,c0.y,c0.z,c0.w,c1.x,c1.y,c1.z,c1.w};
#pragma unroll
      for (int fi = 0; fi < 8; ++fi) {
#pragma unroll
        for (int j4 = 0; j4 < 8; ++j4) {
          const float4 w4 = *(const float4*)(Wc + ((kt * 8 + fi) * 32 + j4 * 4));
          acc0[j4*4+0] = fmaf(va[fi], w4.x, acc0[j4*4+0]);
          acc0[j4*4+1] = fmaf(va[fi], w4.y, acc0[j4*4+1]);
          acc0[j4*4+2] = fmaf(va[fi], w4.z, acc0[j4*4+2]);
          acc0[j4*4+3] = fmaf(va[fi], w4.w, acc0[j4*4+3]);
          acc1[j4*4+0] = fmaf(vb[fi], w4.x, acc1[j4*4+0]);
          acc1[j4*4+1] = fmaf(vb[fi], w4.y, acc1[j4*4+1]);
          acc1[j4*4+2] = fmaf(vb[fi], w4.z, acc1[j4*4+2]);
          acc1[j4*4+3] = fmaf(vb[fi], w4.w, acc1[j4*4+3]);
        }
      }
    }

#pragma unroll
    for (int which = 0; which < 2; ++which) {
      float* a = which ? acc1 : acc0;
      const int t2 = t2a + which;
      float mu = 0.f;
#pragma unroll
      for (int j = 0; j < 32; ++j) { a[j] = fmaxf(a[j], 0.f); mu += a[j]; }
      mu *= (1.f / 32.f);
      float var = 0.f;
#pragma unroll
      for (int j = 0; j < 32; ++j) { float d = a[j] - mu; var += d * d; }
      var *= (1.f / 32.f);
      const float rs = rsqrtf(var + 1e-6f);
      float y[32];
#pragma unroll
      for (int j = 0; j < 32; ++j) {
        y[j] = (a[j] - mu) * rs * g1[j] + be1[j];
        sacc[j] += y[j];
      }
      // bf16 hi/lo, pre-swizzled 16B chunks
      const size_t obase = ((size_t)(b * T2_ + t2) * C_ + c) * 32;
      const int rs4 = t2 & 3;
#pragma unroll
      for (int g = 0; g < 4; ++g) {
        unsigned hq[4], lq[4];
#pragma unroll
        for (int jj = 0; jj < 4; ++jj) {
          const float ya = y[8*g + 2*jj], yb = y[8*g + 2*jj + 1];
          const float ha = bft(ya), hb = bft(yb);
          hq[jj] = (__float_as_uint(ha) >> 16) | (__float_as_uint(hb) & 0xffff0000u);
          lq[jj] = bfpack(ya - ha, yb - hb);
        }
        const int pg = (g ^ rs4) * 8;
        *(uint4*)(Xch + obase + pg) = make_uint4(hq[0], hq[1], hq[2], hq[3]);
        *(uint4*)(Xcl + obase + pg) = make_uint4(lq[0], lq[1], lq[2], lq[3]);
      }
    }
  }

  {
    float* xa = xacc + tt * 2048 + c * 32;
#pragma unroll
    for (int j = 0; j < 32; j += 4)
      *(float4*)(xa + j) = make_float4(sacc[j], sacc[j+1], sacc[j+2], sacc[j+3]);
  }
  __syncthreads();
  for (int idx = tid; idx < 2048; idx += 256) {
    float s = xacc[idx] + xacc[2048 + idx] + xacc[4096 + idx] + xacc[6144 + idx];
    xsp[((size_t)b * 32 + blockIdx.x) * 2048 + idx] = s;
  }
}

// ---------------------------------------------------------------------------
// K2: x_spat reduce, q/k, adj=softmax, ca=sigmoid; A'[c][d] = ca[c]adj[c,d]+I
// ---------------------------------------------------------------------------
__global__ __launch_bounds__(256) void k2_graph(
    const float* __restrict__ xsp, const float* __restrict__ qw,
    const float* __restrict__ qb, const float* __restrict__ kw,
    const float* __restrict__ kb, const float* __restrict__ caw,
    const float* __restrict__ cab, float* __restrict__ Aout)
{
  __shared__ float xs[64 * 32];
  __shared__ float qs[64][32];
  __shared__ float ks[64][32];
  __shared__ float sc[64][64];
  __shared__ float cain[64];
  __shared__ float cav[64];
  const int tid = threadIdx.x;
  const int b = blockIdx.x;

  for (int idx = tid; idx < 2048; idx += 256) {
    float s = 0.f;
    for (int p = 0; p < 32; ++p) s += xsp[((size_t)b * 32 + p) * 2048 + idx];
    xs[idx] = s * (1.f / (float)T2_);
  }
  __syncthreads();

  if (tid < 64) {
    float s = 0.f;
#pragma unroll
    for (int f = 0; f < 32; ++f) s += xs[tid * 32 + f];
    cain[tid] = s * (1.f / 32.f);
  }
  {
    const int cc = tid >> 2, part = tid & 3;
    float aq[8], ak[8];
#pragma unroll
    for (int j = 0; j < 8; ++j) { aq[j] = qb[part*8+j]; ak[j] = kb[part*8+j]; }
    for (int f = 0; f < 32; ++f) {
      const float xv = xs[cc * 32 + f];
#pragma unroll
      for (int j = 0; j < 8; ++j) {
        aq[j] = fmaf(xv, qw[f * 32 + part*8+j], aq[j]);
        ak[j] = fmaf(xv, kw[f * 32 + part*8+j], ak[j]);
      }
    }
#pragma unroll
    for (int j = 0; j < 8; ++j) { qs[cc][part*8+j] = aq[j]; ks[cc][part*8+j] = ak[j]; }
  }
  __syncthreads();
  {
    const int cc = tid >> 2, part = tid & 3;
    for (int dd = part * 16; dd < part * 16 + 16; ++dd) {
      float s = 0.f;
#pragma unroll
      for (int e = 0; e < 32; ++e) s = fmaf(qs[cc][e], ks[dd][e], s);
      sc[cc][dd] = s * 0.1767766953f;
    }
  }
  __syncthreads();
  if (tid < 64) {
    const int cc = tid;
    float m = -1e30f;
    for (int d = 0; d < 64; ++d) m = fmaxf(m, sc[cc][d]);
    float sum = 0.f;
    for (int d = 0; d < 64; ++d) { float e = expf(sc[cc][d] - m); sc[cc][d] = e; sum += e; }
    const float inv = 1.f / sum;
    for (int d = 0; d < 64; ++d) sc[cc][d] *= inv;
    float a = cab[cc];
    for (int d = 0; d < 64; ++d) a = fmaf(cain[d], caw[d * 64 + cc], a);
    cav[cc] = 1.f / (1.f + expf(-a));
  }
  __syncthreads();
  for (int idx = tid; idx < 4096; idx += 256) {
    const int cc = idx >> 6, dd = idx & 63;
    Aout[(size_t)b * 4096 + idx] = cav[cc] * sc[cc][dd] + (cc == dd ? 1.f : 0.f);
  }
}

// ---------------------------------------------------------------------------
// K3: Weff_T[b][d][h][f] = sum_c A'[c][d] mixw[c*32+f][h], written as bf16
// hi/lo with the same g^(h&3) chunk pre-swizzle.  block = (b, 4-h tile);
// lanes = d (Ms rows read as wave-broadcast -> conflict-free).
// ---------------------------------------------------------------------------
__global__ __launch_bounds__(256) void k3_weff(
    const float* __restrict__ Aout, const float* __restrict__ mixw,
    u16* __restrict__ Wth, u16* __restrict__ Wtl)
{
  __shared__ float Ap[4096];   // A'[c][d]
  __shared__ float Ms[2048];   // [cc16][hl4][f32]
  const int tid = threadIdx.x;
  const int b = blockIdx.x >> 5, ht = blockIdx.x & 31;
  const int d = tid & 63, hl = tid >> 6;
  const int h0 = ht * 4;
  const float* Ab = Aout + (size_t)b * 4096;
#pragma unroll
  for (int l = 0; l < 16; ++l) Ap[tid + 256 * l] = Ab[tid + 256 * l];

  float acc[32];
#pragma unroll
  for (int j = 0; j < 32; ++j) acc[j] = 0.f;

  for (int c0 = 0; c0 < 64; c0 += 16) {
    __syncthreads();
    {
      const int i0 = tid * 8;
#pragma unroll
      for (int qd = 0; qd < 2; ++qd) {
        const int i = i0 + qd * 4;
        const int cc = i >> 7, f = (i >> 2) & 31;
        const float4 v = *(const float4*)&mixw[((size_t)((c0+cc)*32 + f))*128 + h0];
        float* mp = &Ms[cc * 128 + f];
        mp[0] = v.x; mp[32] = v.y; mp[64] = v.z; mp[96] = v.w;
      }
    }
    __syncthreads();
#pragma unroll 4
    for (int cc = 0; cc < 16; ++cc) {
      const float a = Ap[(c0 + cc) * 64 + d];
      const float* mrow = &Ms[cc * 128 + hl * 32];
#pragma unroll
      for (int fq = 0; fq < 8; ++fq) {
        const f32x4 m = *(const f32x4*)&mrow[fq * 4];
        acc[fq*4+0] = fmaf(a, m[0], acc[fq*4+0]);
        acc[fq*4+1] = fmaf(a, m[1], acc[fq*4+1]);
        acc[fq*4+2] = fmaf(a, m[2], acc[fq*4+2]);
        acc[fq*4+3] = fmaf(a, m[3], acc[fq*4+3]);
      }
    }
  }

  const int h = h0 + hl;
  const size_t obase = ((size_t)(b * 64 + d) * 128 + h) * 32;
#pragma unroll
  for (int g = 0; g < 4; ++g) {
    unsigned hq[4], lq[4];
#pragma unroll
    for (int jj = 0; jj < 4; ++jj) {
      const float ya = acc[8*g + 2*jj], yb = acc[8*g + 2*jj + 1];
      const float ha = bft(ya), hb = bft(yb);
      hq[jj] = (__float_as_uint(ha) >> 16) | (__float_as_uint(hb) & 0xffff0000u);
      lq[jj] = bfpack(ya - ha, yb - hb);
    }
    const int pg = (g ^ hl) * 8;   // h&3 == hl
    *(uint4*)(Wth + obase + pg) = make_uint4(hq[0], hq[1], hq[2], hq[3]);
    *(uint4*)(Wtl + obase + pg) = make_uint4(lq[0], lq[1], lq[2], lq[3]);
  }
}

// ---------------------------------------------------------------------------
// K4: Xm = LN2(relu(Xc @ Weff + mix_b)) via bf16-split MFMA:
//     Ah@Bh + Ah@Bl + Al@Bh  (AlBl term ~2^-18, dropped).
// BM=64, BN=128, BK=32; 256 thr (4 waves, wave tile 64m x 32n);
// global_load_lds staging (linear LDS, swizzle pre-baked in global layout);
// double-buffered; XCD-bijective block swizzle keeps same-b blocks on 1 XCD.
// ---------------------------------------------------------------------------
__global__ __launch_bounds__(256) void k4_gemm(
    const u16* __restrict__ Agh, const u16* __restrict__ Agl,
    const u16* __restrict__ Bgh, const u16* __restrict__ Bgl,
    const float* __restrict__ mixb, const float* __restrict__ g2,
    const float* __restrict__ be2, float* __restrict__ Xm)
{
  __shared__ __align__(16) u16 lds[2 * 12288];  // per buf: Ah,Al(2048ea) Bh,Bl(4096ea)
  __shared__ float part[64 * 8];
  __shared__ float murs[128];

  const int tid = threadIdx.x;
  const int w = tid >> 6, lane = tid & 63;
  const int x = blockIdx.x;
  const int swz = (x & 7) * 64 + (x >> 3);      // bijective; same-b -> same XCD
  const int b = swz >> 4, mt = swz & 15;
  const int m0 = mt * 64;

  f32x4 acc[4][2];
#pragma unroll
  for (int i = 0; i < 4; ++i)
#pragma unroll
    for (int j = 0; j < 2; ++j) acc[i][j] = (f32x4){0.f, 0.f, 0.f, 0.f};

  const int lrow = lane >> 2, lg = lane & 3;
  const size_t arow  = (size_t)(b * 1024 + m0 + w * 16 + lrow) * 2048 + lg * 8;
  const size_t brow0 = (size_t)b * 262144 + (size_t)(w * 16 + lrow) * 32 + lg * 8;
  const int dA = w * 512;

#define STAGE_K4(kt, buf) do {                                               \
    const int db_ = (buf) * 12288;                                           \
    glds16(Agh + arow + (size_t)(kt) * 32, &lds[db_ + dA]);                  \
    glds16(Agl + arow + (size_t)(kt) * 32, &lds[db_ + 2048 + dA]);           \
    glds16(Bgh + brow0 + (size_t)(kt) * 4096,        &lds[db_ + 4096 + dA]); \
    glds16(Bgh + brow0 + (size_t)(kt) * 4096 + 2048, &lds[db_ + 6144 + dA]); \
    glds16(Bgl + brow0 + (size_t)(kt) * 4096,        &lds[db_ + 8192 + dA]); \
    glds16(Bgl + brow0 + (size_t)(kt) * 4096 + 2048, &lds[db_ + 10240 + dA]);\
  } while (0)

  const int fa = (lane & 15) * 32 + (((lane >> 4) ^ (lane & 3)) * 8);

  int cur = 0;
  STAGE_K4(0, 0);
  __syncthreads();

  for (int kt = 0; kt < 64; ++kt) {
    if (kt < 63) STAGE_K4(kt + 1, cur ^ 1);
    const u16* base = &lds[cur * 12288];
    bf16x8 ah[4], al[4], bh[2], bl[2];
#pragma unroll
    for (int mf = 0; mf < 4; ++mf) {
      ah[mf] = *(const bf16x8*)(base + mf * 512 + fa);
      al[mf] = *(const bf16x8*)(base + 2048 + mf * 512 + fa);
    }
#pragma unroll
    for (int nf = 0; nf < 2; ++nf) {
      bh[nf] = *(const bf16x8*)(base + 4096 + w * 1024 + nf * 512 + fa);
      bl[nf] = *(const bf16x8*)(base + 8192 + w * 1024 + nf * 512 + fa);
    }
#pragma unroll
    for (int mf = 0; mf < 4; ++mf)
#pragma unroll
      for (int nf = 0; nf < 2; ++nf) {
        acc[mf][nf] = __builtin_amdgcn_mfma_f32_16x16x32_bf16(ah[mf], bh[nf], acc[mf][nf], 0, 0, 0);
        acc[mf][nf] = __builtin_amdgcn_mfma_f32_16x16x32_bf16(ah[mf], bl[nf], acc[mf][nf], 0, 0, 0);
        acc[mf][nf] = __builtin_amdgcn_mfma_f32_16x16x32_bf16(al[mf], bh[nf], acc[mf][nf], 0, 0, 0);
      }
    __syncthreads();
    cur ^= 1;
  }
#undef STAGE_K4

  // epilogue: +bias, relu, LN over 128
  const int c0 = w * 32 + (lane & 15);
  const float bias0 = mixb[c0], bias1 = mixb[c0 + 16];
#pragma unroll
  for (int mf = 0; mf < 4; ++mf)
#pragma unroll
    for (int r = 0; r < 4; ++r) {
      float v0 = fmaxf(acc[mf][0][r] + bias0, 0.f);
      float v1 = fmaxf(acc[mf][1][r] + bias1, 0.f);
      acc[mf][0][r] = v0; acc[mf][1][r] = v1;
      float s1 = v0 + v1, s2 = v0 * v0 + v1 * v1;
      s1 += __shfl_xor(s1, 1);  s2 += __shfl_xor(s2, 1);
      s1 += __shfl_xor(s1, 2);  s2 += __shfl_xor(s2, 2);
      s1 += __shfl_xor(s1, 4);  s2 += __shfl_xor(s2, 4);
      s1 += __shfl_xor(s1, 8);  s2 += __shfl_xor(s2, 8);
      if ((lane & 15) == 0) {
        const int row = mf * 16 + (lane >> 4) * 4 + r;
        part[row * 8 + w * 2] = s1;
        part[row * 8 + w * 2 + 1] = s2;
      }
    }
  __syncthreads();
  if (tid < 64) {
    const float s1 = part[tid*8] + part[tid*8+2] + part[tid*8+4] + part[tid*8+6];
    const float s2 = part[tid*8+1] + part[tid*8+3] + part[tid*8+5] + part[tid*8+7];
    const float mu = s1 * (1.f / 128.f);
    const float var = s2 * (1.f / 128.f) - mu * mu;
    murs[tid * 2] = mu;
    murs[tid * 2 + 1] = rsqrtf(var + 1e-6f);
  }
  __syncthreads();
  const float g20 = g2[c0], g21 = g2[c0 + 16];
  const float b20 = be2[c0], b21 = be2[c0 + 16];
#pragma unroll
  for (int mf = 0; mf < 4; ++mf)
#pragma unroll
    for (int r = 0; r < 4; ++r) {
      const int row = mf * 16 + (lane >> 4) * 4 + r;
      const float mu = murs[row * 2], rs = murs[row * 2 + 1];
      float* op = Xm + (size_t)(b * 1024 + m0 + row) * 128;
      op[c0]      = (acc[mf][0][r] - mu) * rs * g20 + b20;
      op[c0 + 16] = (acc[mf][1][r] - mu) * rs * g21 + b21;
    }
}

// ---------------------------------------------------------------------------
// K5: LIF scan, 4096 chains spread over 64 blocks/CUs
// ---------------------------------------------------------------------------
__global__ __launch_bounds__(64) void k5_lif(
    const float* __restrict__ Xm, const float* __restrict__ dl,
    float* __restrict__ fs)
{
  const int id = blockIdx.x * 64 + threadIdx.x;
  const int b = id >> 7, h = id & 127;
  const float decay = 1.f / (1.f + expf(-dl[h]));
  float mem = 0.f, cnt = 0.f;
  const float* p = Xm + (size_t)b * T2_ * H_ + h;
#pragma unroll 16
  for (int t = 0; t < T2_; ++t) {
    const float xv = p[(size_t)t * H_];
    mem = fmaf(mem, decay, xv);
    const float sp = ((mem - 0.5f) > 0.f) ? 1.f : 0.f;
    cnt += sp;
    mem -= 0.5f * sp;
  }
  fs[b * H_ + h] = cnt;
}

// ---------------------------------------------------------------------------
// K6: head
// ---------------------------------------------------------------------------
__global__ __launch_bounds__(256) void k6_head(
    const float* __restrict__ fs, const float* __restrict__ fcw,
    const float* __restrict__ fcb, const float* __restrict__ ow,
    const float* __restrict__ ob, float* __restrict__ out)
{
  __shared__ float f[32 * 128];
  __shared__ float fr[32 * 128];
  __shared__ float red[256];
  const int tid = threadIdx.x;
  float tot = 0.f;
  for (int idx = tid; idx < 4096; idx += 256) {
    const float v = fs[idx];
    f[idx] = v * (1.f / (float)T2_);
    tot += v;
  }
  red[tid] = tot;
  __syncthreads();
  for (int s = 128; s > 0; s >>= 1) {
    if (tid < s) red[tid] += red[tid + s];
    __syncthreads();
  }
  {
    const int bb = tid >> 3, og = tid & 7;
    float a[16];
#pragma unroll
    for (int j = 0; j < 16; ++j) a[j] = fcb[og * 16 + j];
    for (int hh = 0; hh < 128; ++hh) {
      const float fv = f[bb * 128 + hh];
#pragma unroll
      for (int j = 0; j < 16; ++j)
        a[j] = fmaf(fv, fcw[hh * 128 + og * 16 + j], a[j]);
    }
#pragma unroll
    for (int j = 0; j < 16; ++j) fr[bb * 128 + og * 16 + j] = fmaxf(a[j], 0.f);
  }
  __syncthreads();
  if (tid < 128) {
    const int bb = tid >> 2, cls = tid & 3;
    float a = ob[cls];
    for (int o = 0; o < 128; ++o) a = fmaf(fr[bb * 128 + o], ow[o * 4 + cls], a);
    out[bb * 4 + cls] = a;
  }
  if (tid == 0) out[128] = red[0] * (1.f / (4096.f * 1024.f));
}

// ---------------------------------------------------------------------------
extern "C" void kernel_launch(void* const* d_in, const int* in_sizes, int n_in,
                              void* d_out, int out_size, void* d_ws, size_t ws_size,
                              hipStream_t stream) {
  const float* X     = (const float*)d_in[0];
  const float* convw = (const float*)d_in[1];
  const float* convb = (const float*)d_in[2];
  const float* ln1s  = (const float*)d_in[3];
  const float* ln1b  = (const float*)d_in[4];
  const float* qw    = (const float*)d_in[5];
  const float* qb    = (const float*)d_in[6];
  const float* kw    = (const float*)d_in[7];
  const float* kb    = (const float*)d_in[8];
  const float* caw   = (const float*)d_in[9];
  const float* cab   = (const float*)d_in[10];
  const float* mixw  = (const float*)d_in[11];
  const float* mixb  = (const float*)d_in[12];
  const float* ln2s  = (const float*)d_in[13];
  const float* ln2b  = (const float*)d_in[14];
  const float* dl    = (const float*)d_in[15];
  const float* fcw   = (const float*)d_in[16];
  const float* fcb   = (const float*)d_in[17];
  const float* outw  = (const float*)d_in[18];
  const float* outb  = (const float*)d_in[19];

  float* ws  = (float*)d_ws;
  u16* Xch   = (u16*)(ws + OFF_XCH);
  u16* Xcl   = (u16*)(ws + OFF_XCL);
  u16* Wth   = (u16*)(ws + OFF_WTH);
  u16* Wtl   = (u16*)(ws + OFF_WTL);
  float* xsp = ws + OFF_XSP;
  float* Aou = ws + OFF_A;
  float* Xm  = ws + OFF_XM;
  float* fs  = ws + OFF_A;   // reuse (A' dead after k3)

  dim3 g1(32, 32);
  k1_conv_ln<<<g1, 256, 0, stream>>>(X, convw, convb, ln1s, ln1b, Xch, Xcl, xsp);
  k2_graph<<<32, 256, 0, stream>>>(xsp, qw, qb, kw, kb, caw, cab, Aou);
  k3_weff<<<1024, 256, 0, stream>>>(Aou, mixw, Wth, Wtl);
  k4_gemm<<<512, 256, 0, stream>>>(Xch, Xcl, Wth, Wtl, mixb, ln2s, ln2b, Xm);
  k5_lif<<<64, 64, 0, stream>>>(Xm, dl, fs);
  k6_head<<<1, 256, 0, stream>>>(fs, fcw, fcb, outw, outb, (float*)d_out);
}

// Round 4
// 494.920 us; speedup vs baseline: 1.5390x; 1.0191x over previous
//
#include <hip/hip_runtime.h>
#include <math.h>

#define B_    32
#define T_    2048
#define T2_   1024
#define C_    64
#define FI_   8
#define FO_   32
#define K_    2048   // C_*CONV_F
#define H_    128

typedef unsigned short u16;
typedef short bf16x8 __attribute__((ext_vector_type(8)));
typedef float f32x4 __attribute__((ext_vector_type(4)));

// workspace offsets (in FLOAT units); total 81,920,000 floats = same footprint
// as the round-2 kernel that passed (so ws_size is known sufficient).
#define OFF_XCH  ((size_t)0)          // bf16 hi Xc: 67,108,864 u16 = 33,554,432 f
#define OFF_XCL  ((size_t)33554432)   // bf16 lo Xc
#define OFF_WTH  ((size_t)67108864)   // bf16 hi Weff_T: 8,388,608 u16
#define OFF_WTL  ((size_t)71303168)
#define OFF_XSP  ((size_t)75497472)   // 32*32*2048 f32
#define OFF_A    ((size_t)77594624)   // 32*64*64 f32 (A'); reused later for fs
#define OFF_XM   ((size_t)77725696)   // 32*1024*128 f32

// ---- bf16 split helpers (RTNE) -------------------------------------------
__device__ __forceinline__ float bft(float x) {  // value of bf16-rounded x
  unsigned u = __float_as_uint(x);
  u = (u + 0x7fffu + ((u >> 16) & 1u)) & 0xffff0000u;
  return __uint_as_float(u);
}
__device__ __forceinline__ unsigned bfpack(float a, float b) { // round both
  unsigned ua = __float_as_uint(a); ua = (ua + 0x7fffu + ((ua >> 16) & 1u)) >> 16;
  unsigned ub = __float_as_uint(b); ub = (ub + 0x7fffu + ((ub >> 16) & 1u)) & 0xffff0000u;
  return ua | ub;
}

// async global->LDS, 16B per lane; LDS dest must be wave-uniform base
__device__ __forceinline__ void glds16(const u16* g, u16* l) {
  auto gp = reinterpret_cast<const __attribute__((address_space(1))) unsigned int*>(
      reinterpret_cast<uintptr_t>(g));
  auto lp = reinterpret_cast<__attribute__((address_space(3))) unsigned int*>(
      reinterpret_cast<uintptr_t>(l));
  __builtin_amdgcn_global_load_lds(gp, lp, 16, 0, 0);
}

// ---------------------------------------------------------------------------
// K1 (rewritten for occupancy): conv(5x1,s2,SAME)+bias+relu+LN(32) -> bf16
// hi/lo Xc (pre-swizzled 16B chunks), xsp partials.
// grid (32 t2-tiles, 32 b), block 256 = 4 waves; wave tt handles t2 =
// t2base + 4*it + tt (t2 is WAVE-UNIFORM -> X loads are one 2KB coalesced
// stream; tt-interleave makes concurrent waves share conv-window rows in L1).
// x_spat partial accumulated straight into LDS xacc[4][64][33] (pad 33:
// bank=(c+j)%32 -> 2-way, free) - kills the 32-reg sacc array.
// Live regs ~80 -> __launch_bounds__(256,4): 4 waves/SIMD, 4 blocks/CU.
// ---------------------------------------------------------------------------
__global__ __launch_bounds__(256, 4) void k1_conv_ln(
    const float* __restrict__ X, const float* __restrict__ Wc,
    const float* __restrict__ bc, const float* __restrict__ g1,
    const float* __restrict__ be1, u16* __restrict__ Xch,
    u16* __restrict__ Xcl, float* __restrict__ xsp)
{
  __shared__ float xacc[4 * 64 * 33];   // 33.8 KB
  const int tid = threadIdx.x;
  const int c  = tid & 63;
  const int tt = tid >> 6;
  const int b  = blockIdx.y;
  const int t2base = blockIdx.x * 32;

  for (int i = tid; i < 4 * 64 * 33; i += 256) xacc[i] = 0.f;
  __syncthreads();
  float* myacc = &xacc[(tt * 64 + c) * 33];

#pragma unroll 1
  for (int it = 0; it < 8; ++it) {
    const int t2 = t2base + it * 4 + tt;
    float a[32];
#pragma unroll
    for (int j = 0; j < 32; ++j) a[j] = bc[j];

#pragma unroll
    for (int kt = 0; kt < 5; ++kt) {
      const int ta = 2 * t2 + kt - 1;
      float4 x0 = make_float4(0.f, 0.f, 0.f, 0.f), x1 = x0;
      if (ta >= 0 && ta < T_) {
        const float* p = X + (((size_t)b * T_ + ta) * C_ + c) * FI_;
        x0 = *(const float4*)p; x1 = *(const float4*)(p + 4);
      }
      float xv[8] = {x0.x, x0.y, x0.z, x0.w, x1.x, x1.y, x1.z, x1.w};
#pragma unroll
      for (int fi = 0; fi < 8; ++fi) {
#pragma unroll
        for (int j4 = 0; j4 < 8; ++j4) {
          const float4 w4 = *(const float4*)(Wc + ((kt * 8 + fi) * 32 + j4 * 4));
          a[j4*4+0] = fmaf(xv[fi], w4.x, a[j4*4+0]);
          a[j4*4+1] = fmaf(xv[fi], w4.y, a[j4*4+1]);
          a[j4*4+2] = fmaf(xv[fi], w4.z, a[j4*4+2]);
          a[j4*4+3] = fmaf(xv[fi], w4.w, a[j4*4+3]);
        }
      }
    }

    // relu + LN over 32 features (in place)
    float mu = 0.f;
#pragma unroll
    for (int j = 0; j < 32; ++j) { a[j] = fmaxf(a[j], 0.f); mu += a[j]; }
    mu *= (1.f / 32.f);
    float var = 0.f;
#pragma unroll
    for (int j = 0; j < 32; ++j) { float d = a[j] - mu; var += d * d; }
    var *= (1.f / 32.f);
    const float rs = rsqrtf(var + 1e-6f);
#pragma unroll
    for (int j = 0; j < 32; ++j) {
      a[j] = (a[j] - mu) * rs * g1[j] + be1[j];
      myacc[j] += a[j];
    }

    // bf16 hi/lo, pre-swizzled 16B chunks; lanes (=c) write dense 64B each
    const size_t obase = ((size_t)(b * T2_ + t2) * C_ + c) * 32;
    const int rs4 = t2 & 3;
#pragma unroll
    for (int g = 0; g < 4; ++g) {
      unsigned hq[4], lq[4];
#pragma unroll
      for (int jj = 0; jj < 4; ++jj) {
        const float ya = a[8*g + 2*jj], yb = a[8*g + 2*jj + 1];
        const float ha = bft(ya), hb = bft(yb);
        hq[jj] = (__float_as_uint(ha) >> 16) | (__float_as_uint(hb) & 0xffff0000u);
        lq[jj] = bfpack(ya - ha, yb - hb);
      }
      const int pg = (g ^ rs4) * 8;
      *(uint4*)(Xch + obase + pg) = make_uint4(hq[0], hq[1], hq[2], hq[3]);
      *(uint4*)(Xcl + obase + pg) = make_uint4(lq[0], lq[1], lq[2], lq[3]);
    }
  }

  __syncthreads();
  for (int i = tid; i < 2048; i += 256) {
    const int cc = i >> 5, j = i & 31;
    const float s = xacc[(0 * 64 + cc) * 33 + j] + xacc[(1 * 64 + cc) * 33 + j]
                  + xacc[(2 * 64 + cc) * 33 + j] + xacc[(3 * 64 + cc) * 33 + j];
    xsp[((size_t)b * 32 + blockIdx.x) * 2048 + i] = s;
  }
}

// ---------------------------------------------------------------------------
// K2: x_spat reduce, q/k, adj=softmax, ca=sigmoid; A'[c][d] = ca[c]adj[c,d]+I
// ---------------------------------------------------------------------------
__global__ __launch_bounds__(256) void k2_graph(
    const float* __restrict__ xsp, const float* __restrict__ qw,
    const float* __restrict__ qb, const float* __restrict__ kw,
    const float* __restrict__ kb, const float* __restrict__ caw,
    const float* __restrict__ cab, float* __restrict__ Aout)
{
  __shared__ float xs[64 * 32];
  __shared__ float qs[64][32];
  __shared__ float ks[64][32];
  __shared__ float sc[64][64];
  __shared__ float cain[64];
  __shared__ float cav[64];
  const int tid = threadIdx.x;
  const int b = blockIdx.x;

  for (int idx = tid; idx < 2048; idx += 256) {
    float s = 0.f;
    for (int p = 0; p < 32; ++p) s += xsp[((size_t)b * 32 + p) * 2048 + idx];
    xs[idx] = s * (1.f / (float)T2_);
  }
  __syncthreads();

  if (tid < 64) {
    float s = 0.f;
#pragma unroll
    for (int f = 0; f < 32; ++f) s += xs[tid * 32 + f];
    cain[tid] = s * (1.f / 32.f);
  }
  {
    const int cc = tid >> 2, part = tid & 3;
    float aq[8], ak[8];
#pragma unroll
    for (int j = 0; j < 8; ++j) { aq[j] = qb[part*8+j]; ak[j] = kb[part*8+j]; }
    for (int f = 0; f < 32; ++f) {
      const float xv = xs[cc * 32 + f];
#pragma unroll
      for (int j = 0; j < 8; ++j) {
        aq[j] = fmaf(xv, qw[f * 32 + part*8+j], aq[j]);
        ak[j] = fmaf(xv, kw[f * 32 + part*8+j], ak[j]);
      }
    }
#pragma unroll
    for (int j = 0; j < 8; ++j) { qs[cc][part*8+j] = aq[j]; ks[cc][part*8+j] = ak[j]; }
  }
  __syncthreads();
  {
    const int cc = tid >> 2, part = tid & 3;
    for (int dd = part * 16; dd < part * 16 + 16; ++dd) {
      float s = 0.f;
#pragma unroll
      for (int e = 0; e < 32; ++e) s = fmaf(qs[cc][e], ks[dd][e], s);
      sc[cc][dd] = s * 0.1767766953f;
    }
  }
  __syncthreads();
  if (tid < 64) {
    const int cc = tid;
    float m = -1e30f;
    for (int d = 0; d < 64; ++d) m = fmaxf(m, sc[cc][d]);
    float sum = 0.f;
    for (int d = 0; d < 64; ++d) { float e = expf(sc[cc][d] - m); sc[cc][d] = e; sum += e; }
    const float inv = 1.f / sum;
    for (int d = 0; d < 64; ++d) sc[cc][d] *= inv;
    float a = cab[cc];
    for (int d = 0; d < 64; ++d) a = fmaf(cain[d], caw[d * 64 + cc], a);
    cav[cc] = 1.f / (1.f + expf(-a));
  }
  __syncthreads();
  for (int idx = tid; idx < 4096; idx += 256) {
    const int cc = idx >> 6, dd = idx & 63;
    Aout[(size_t)b * 4096 + idx] = cav[cc] * sc[cc][dd] + (cc == dd ? 1.f : 0.f);
  }
}

// ---------------------------------------------------------------------------
// K3: Weff_T[b][d][h][f] = sum_c A'[c][d] mixw[c*32+f][h], written as bf16
// hi/lo with the same g^(h&3) chunk pre-swizzle.  block = (b, 4-h tile);
// lanes = d (Ms rows read as wave-broadcast -> conflict-free).
// ---------------------------------------------------------------------------
__global__ __launch_bounds__(256) void k3_weff(
    const float* __restrict__ Aout, const float* __restrict__ mixw,
    u16* __restrict__ Wth, u16* __restrict__ Wtl)
{
  __shared__ float Ap[4096];   // A'[c][d]
  __shared__ float Ms[2048];   // [cc16][hl4][f32]
  const int tid = threadIdx.x;
  const int b = blockIdx.x >> 5, ht = blockIdx.x & 31;
  const int d = tid & 63, hl = tid >> 6;
  const int h0 = ht * 4;
  const float* Ab = Aout + (size_t)b * 4096;
#pragma unroll
  for (int l = 0; l < 16; ++l) Ap[tid + 256 * l] = Ab[tid + 256 * l];

  float acc[32];
#pragma unroll
  for (int j = 0; j < 32; ++j) acc[j] = 0.f;

  for (int c0 = 0; c0 < 64; c0 += 16) {
    __syncthreads();
    {
      const int i0 = tid * 8;
#pragma unroll
      for (int qd = 0; qd < 2; ++qd) {
        const int i = i0 + qd * 4;
        const int cc = i >> 7, f = (i >> 2) & 31;
        const float4 v = *(const float4*)&mixw[((size_t)((c0+cc)*32 + f))*128 + h0];
        float* mp = &Ms[cc * 128 + f];
        mp[0] = v.x; mp[32] = v.y; mp[64] = v.z; mp[96] = v.w;
      }
    }
    __syncthreads();
#pragma unroll 4
    for (int cc = 0; cc < 16; ++cc) {
      const float a = Ap[(c0 + cc) * 64 + d];
      const float* mrow = &Ms[cc * 128 + hl * 32];
#pragma unroll
      for (int fq = 0; fq < 8; ++fq) {
        const f32x4 m = *(const f32x4*)&mrow[fq * 4];
        acc[fq*4+0] = fmaf(a, m[0], acc[fq*4+0]);
        acc[fq*4+1] = fmaf(a, m[1], acc[fq*4+1]);
        acc[fq*4+2] = fmaf(a, m[2], acc[fq*4+2]);
        acc[fq*4+3] = fmaf(a, m[3], acc[fq*4+3]);
      }
    }
  }

  const int h = h0 + hl;
  const size_t obase = ((size_t)(b * 64 + d) * 128 + h) * 32;
#pragma unroll
  for (int g = 0; g < 4; ++g) {
    unsigned hq[4], lq[4];
#pragma unroll
    for (int jj = 0; jj < 4; ++jj) {
      const float ya = acc[8*g + 2*jj], yb = acc[8*g + 2*jj + 1];
      const float ha = bft(ya), hb = bft(yb);
      hq[jj] = (__float_as_uint(ha) >> 16) | (__float_as_uint(hb) & 0xffff0000u);
      lq[jj] = bfpack(ya - ha, yb - hb);
    }
    const int pg = (g ^ hl) * 8;   // h&3 == hl
    *(uint4*)(Wth + obase + pg) = make_uint4(hq[0], hq[1], hq[2], hq[3]);
    *(uint4*)(Wtl + obase + pg) = make_uint4(lq[0], lq[1], lq[2], lq[3]);
  }
}

// ---------------------------------------------------------------------------
// K4: Xm = LN2(relu(Xc @ Weff + mix_b)) via bf16-split MFMA:
//     Ah@Bh + Ah@Bl + Al@Bh  (AlBl term ~2^-18, dropped).
// BM=64, BN=128, BK=32; 256 thr (4 waves, wave tile 64m x 32n);
// global_load_lds staging (linear LDS, swizzle pre-baked in global layout);
// double-buffered; XCD-bijective block swizzle keeps same-b blocks on 1 XCD.
// ---------------------------------------------------------------------------
__global__ __launch_bounds__(256) void k4_gemm(
    const u16* __restrict__ Agh, const u16* __restrict__ Agl,
    const u16* __restrict__ Bgh, const u16* __restrict__ Bgl,
    const float* __restrict__ mixb, const float* __restrict__ g2,
    const float* __restrict__ be2, float* __restrict__ Xm)
{
  __shared__ __align__(16) u16 lds[2 * 12288];  // per buf: Ah,Al(2048ea) Bh,Bl(4096ea)
  __shared__ float part[64 * 8];
  __shared__ float murs[128];

  const int tid = threadIdx.x;
  const int w = tid >> 6, lane = tid & 63;
  const int x = blockIdx.x;
  const int swz = (x & 7) * 64 + (x >> 3);      // bijective; same-b -> same XCD
  const int b = swz >> 4, mt = swz & 15;
  const int m0 = mt * 64;

  f32x4 acc[4][2];
#pragma unroll
  for (int i = 0; i < 4; ++i)
#pragma unroll
    for (int j = 0; j < 2; ++j) acc[i][j] = (f32x4){0.f, 0.f, 0.f, 0.f};

  const int lrow = lane >> 2, lg = lane & 3;
  const size_t arow  = (size_t)(b * 1024 + m0 + w * 16 + lrow) * 2048 + lg * 8;
  const size_t brow0 = (size_t)b * 262144 + (size_t)(w * 16 + lrow) * 32 + lg * 8;
  const int dA = w * 512;

#define STAGE_K4(kt, buf) do {                                               \
    const int db_ = (buf) * 12288;                                           \
    glds16(Agh + arow + (size_t)(kt) * 32, &lds[db_ + dA]);                  \
    glds16(Agl + arow + (size_t)(kt) * 32, &lds[db_ + 2048 + dA]);           \
    glds16(Bgh + brow0 + (size_t)(kt) * 4096,        &lds[db_ + 4096 + dA]); \
    glds16(Bgh + brow0 + (size_t)(kt) * 4096 + 2048, &lds[db_ + 6144 + dA]); \
    glds16(Bgl + brow0 + (size_t)(kt) * 4096,        &lds[db_ + 8192 + dA]); \
    glds16(Bgl + brow0 + (size_t)(kt) * 4096 + 2048, &lds[db_ + 10240 + dA]);\
  } while (0)

  const int fa = (lane & 15) * 32 + (((lane >> 4) ^ (lane & 3)) * 8);

  int cur = 0;
  STAGE_K4(0, 0);
  __syncthreads();

  for (int kt = 0; kt < 64; ++kt) {
    if (kt < 63) STAGE_K4(kt + 1, cur ^ 1);
    const u16* base = &lds[cur * 12288];
    bf16x8 ah[4], al[4], bh[2], bl[2];
#pragma unroll
    for (int mf = 0; mf < 4; ++mf) {
      ah[mf] = *(const bf16x8*)(base + mf * 512 + fa);
      al[mf] = *(const bf16x8*)(base + 2048 + mf * 512 + fa);
    }
#pragma unroll
    for (int nf = 0; nf < 2; ++nf) {
      bh[nf] = *(const bf16x8*)(base + 4096 + w * 1024 + nf * 512 + fa);
      bl[nf] = *(const bf16x8*)(base + 8192 + w * 1024 + nf * 512 + fa);
    }
#pragma unroll
    for (int mf = 0; mf < 4; ++mf)
#pragma unroll
      for (int nf = 0; nf < 2; ++nf) {
        acc[mf][nf] = __builtin_amdgcn_mfma_f32_16x16x32_bf16(ah[mf], bh[nf], acc[mf][nf], 0, 0, 0);
        acc[mf][nf] = __builtin_amdgcn_mfma_f32_16x16x32_bf16(ah[mf], bl[nf], acc[mf][nf], 0, 0, 0);
        acc[mf][nf] = __builtin_amdgcn_mfma_f32_16x16x32_bf16(al[mf], bh[nf], acc[mf][nf], 0, 0, 0);
      }
    __syncthreads();
    cur ^= 1;
  }
#undef STAGE_K4

  // epilogue: +bias, relu, LN over 128
  const int c0 = w * 32 + (lane & 15);
  const float bias0 = mixb[c0], bias1 = mixb[c0 + 16];
#pragma unroll
  for (int mf = 0; mf < 4; ++mf)
#pragma unroll
    for (int r = 0; r < 4; ++r) {
      float v0 = fmaxf(acc[mf][0][r] + bias0, 0.f);
      float v1 = fmaxf(acc[mf][1][r] + bias1, 0.f);
      acc[mf][0][r] = v0; acc[mf][1][r] = v1;
      float s1 = v0 + v1, s2 = v0 * v0 + v1 * v1;
      s1 += __shfl_xor(s1, 1);  s2 += __shfl_xor(s2, 1);
      s1 += __shfl_xor(s1, 2);  s2 += __shfl_xor(s2, 2);
      s1 += __shfl_xor(s1, 4);  s2 += __shfl_xor(s2, 4);
      s1 += __shfl_xor(s1, 8);  s2 += __shfl_xor(s2, 8);
      if ((lane & 15) == 0) {
        const int row = mf * 16 + (lane >> 4) * 4 + r;
        part[row * 8 + w * 2] = s1;
        part[row * 8 + w * 2 + 1] = s2;
      }
    }
  __syncthreads();
  if (tid < 64) {
    const float s1 = part[tid*8] + part[tid*8+2] + part[tid*8+4] + part[tid*8+6];
    const float s2 = part[tid*8+1] + part[tid*8+3] + part[tid*8+5] + part[tid*8+7];
    const float mu = s1 * (1.f / 128.f);
    const float var = s2 * (1.f / 128.f) - mu * mu;
    murs[tid * 2] = mu;
    murs[tid * 2 + 1] = rsqrtf(var + 1e-6f);
  }
  __syncthreads();
  const float g20 = g2[c0], g21 = g2[c0 + 16];
  const float b20 = be2[c0], b21 = be2[c0 + 16];
#pragma unroll
  for (int mf = 0; mf < 4; ++mf)
#pragma unroll
    for (int r = 0; r < 4; ++r) {
      const int row = mf * 16 + (lane >> 4) * 4 + r;
      const float mu = murs[row * 2], rs = murs[row * 2 + 1];
      float* op = Xm + (size_t)(b * 1024 + m0 + row) * 128;
      op[c0]      = (acc[mf][0][r] - mu) * rs * g20 + b20;
      op[c0 + 16] = (acc[mf][1][r] - mu) * rs * g21 + b21;
    }
}

// ---------------------------------------------------------------------------
// K5: LIF scan, 4096 chains spread over 64 blocks/CUs
// ---------------------------------------------------------------------------
__global__ __launch_bounds__(64) void k5_lif(
    const float* __restrict__ Xm, const float* __restrict__ dl,
    float* __restrict__ fs)
{
  const int id = blockIdx.x * 64 + threadIdx.x;
  const int b = id >> 7, h = id & 127;
  const float decay = 1.f / (1.f + expf(-dl[h]));
  float mem = 0.f, cnt = 0.f;
  const float* p = Xm + (size_t)b * T2_ * H_ + h;
#pragma unroll 16
  for (int t = 0; t < T2_; ++t) {
    const float xv = p[(size_t)t * H_];
    mem = fmaf(mem, decay, xv);
    const float sp = ((mem - 0.5f) > 0.f) ? 1.f : 0.f;
    cnt += sp;
    mem -= 0.5f * sp;
  }
  fs[b * H_ + h] = cnt;
}

// ---------------------------------------------------------------------------
// K6: head
// ---------------------------------------------------------------------------
__global__ __launch_bounds__(256) void k6_head(
    const float* __restrict__ fs, const float* __restrict__ fcw,
    const float* __restrict__ fcb, const float* __restrict__ ow,
    const float* __restrict__ ob, float* __restrict__ out)
{
  __shared__ float f[32 * 128];
  __shared__ float fr[32 * 128];
  __shared__ float red[256];
  const int tid = threadIdx.x;
  float tot = 0.f;
  for (int idx = tid; idx < 4096; idx += 256) {
    const float v = fs[idx];
    f[idx] = v * (1.f / (float)T2_);
    tot += v;
  }
  red[tid] = tot;
  __syncthreads();
  for (int s = 128; s > 0; s >>= 1) {
    if (tid < s) red[tid] += red[tid + s];
    __syncthreads();
  }
  {
    const int bb = tid >> 3, og = tid & 7;
    float a[16];
#pragma unroll
    for (int j = 0; j < 16; ++j) a[j] = fcb[og * 16 + j];
    for (int hh = 0; hh < 128; ++hh) {
      const float fv = f[bb * 128 + hh];
#pragma unroll
      for (int j = 0; j < 16; ++j)
        a[j] = fmaf(fv, fcw[hh * 128 + og * 16 + j], a[j]);
    }
#pragma unroll
    for (int j = 0; j < 16; ++j) fr[bb * 128 + og * 16 + j] = fmaxf(a[j], 0.f);
  }
  __syncthreads();
  if (tid < 128) {
    const int bb = tid >> 2, cls = tid & 3;
    float a = ob[cls];
    for (int o = 0; o < 128; ++o) a = fmaf(fr[bb * 128 + o], ow[o * 4 + cls], a);
    out[bb * 4 + cls] = a;
  }
  if (tid == 0) out[128] = red[0] * (1.f / (4096.f * 1024.f));
}

// ---------------------------------------------------------------------------
extern "C" void kernel_launch(void* const* d_in, const int* in_sizes, int n_in,
                              void* d_out, int out_size, void* d_ws, size_t ws_size,
                              hipStream_t stream) {
  const float* X     = (const float*)d_in[0];
  const float* convw = (const float*)d_in[1];
  const float* convb = (const float*)d_in[2];
  const float* ln1s  = (const float*)d_in[3];
  const float* ln1b  = (const float*)d_in[4];
  const float* qw    = (const float*)d_in[5];
  const float* qb    = (const float*)d_in[6];
  const float* kw    = (const float*)d_in[7];
  const float* kb    = (const float*)d_in[8];
  const float* caw   = (const float*)d_in[9];
  const float* cab   = (const float*)d_in[10];
  const float* mixw  = (const float*)d_in[11];
  const float* mixb  = (const float*)d_in[12];
  const float* ln2s  = (const float*)d_in[13];
  const float* ln2b  = (const float*)d_in[14];
  const float* dl    = (const float*)d_in[15];
  const float* fcw   = (const float*)d_in[16];
  const float* fcb   = (const float*)d_in[17];
  const float* outw  = (const float*)d_in[18];
  const float* outb  = (const float*)d_in[19];

  float* ws  = (float*)d_ws;
  u16* Xch   = (u16*)(ws + OFF_XCH);
  u16* Xcl   = (u16*)(ws + OFF_XCL);
  u16* Wth   = (u16*)(ws + OFF_WTH);
  u16* Wtl   = (u16*)(ws + OFF_WTL);
  float* xsp = ws + OFF_XSP;
  float* Aou = ws + OFF_A;
  float* Xm  = ws + OFF_XM;
  float* fs  = ws + OFF_A;   // reuse (A' dead after k3)

  dim3 g1(32, 32);
  k1_conv_ln<<<g1, 256, 0, stream>>>(X, convw, convb, ln1s, ln1b, Xch, Xcl, xsp);
  k2_graph<<<32, 256, 0, stream>>>(xsp, qw, qb, kw, kb, caw, cab, Aou);
  k3_weff<<<1024, 256, 0, stream>>>(Aou, mixw, Wth, Wtl);
  k4_gemm<<<512, 256, 0, stream>>>(Xch, Xcl, Wth, Wtl, mixb, ln2s, ln2b, Xm);
  k5_lif<<<64, 64, 0, stream>>>(Xm, dl, fs);
  k6_head<<<1, 256, 0, stream>>>(fs, fcw, fcb, outw, outb, (float*)d_out);
}

// Round 5
// 387.918 us; speedup vs baseline: 1.9636x; 1.2758x over previous
//
#include <hip/hip_runtime.h>
#include <math.h>

#define B_    32
#define T_    2048
#define T2_   1024
#define C_    64
#define FI_   8
#define FO_   32
#define K_    2048   // C_*CONV_F
#define H_    128

typedef unsigned short u16;
typedef short bf16x8 __attribute__((ext_vector_type(8)));
typedef float f32x4 __attribute__((ext_vector_type(4)));

// workspace offsets (in FLOAT units)
#define OFF_XCH  ((size_t)0)          // bf16 hi Xc
#define OFF_XCL  ((size_t)33554432)   // bf16 lo Xc
#define OFF_WTH  ((size_t)67108864)   // bf16 hi Weff_T
#define OFF_WTL  ((size_t)71303168)
#define OFF_XSP  ((size_t)75497472)   // 32*32*2048 f32
#define OFF_A    ((size_t)77594624)   // 32*64*64 f32 (A'); reused later for fs
#define OFF_XM   ((size_t)77725696)   // 32*1024*128 f32

// ---- bf16 split helpers (RTNE) -------------------------------------------
__device__ __forceinline__ float bft(float x) {  // value of bf16-rounded x
  unsigned u = __float_as_uint(x);
  u = (u + 0x7fffu + ((u >> 16) & 1u)) & 0xffff0000u;
  return __uint_as_float(u);
}
__device__ __forceinline__ unsigned bfpack(float a, float b) { // round both
  unsigned ua = __float_as_uint(a); ua = (ua + 0x7fffu + ((ua >> 16) & 1u)) >> 16;
  unsigned ub = __float_as_uint(b); ub = (ub + 0x7fffu + ((ub >> 16) & 1u)) & 0xffff0000u;
  return ua | ub;
}

// async global->LDS, 16B per lane; LDS dest must be wave-uniform base
__device__ __forceinline__ void glds16(const u16* g, u16* l) {
  auto gp = reinterpret_cast<const __attribute__((address_space(1))) unsigned int*>(
      reinterpret_cast<uintptr_t>(g));
  auto lp = reinterpret_cast<__attribute__((address_space(3))) unsigned int*>(
      reinterpret_cast<uintptr_t>(l));
  __builtin_amdgcn_global_load_lds(gp, lp, 16, 0, 0);
}

// ---------------------------------------------------------------------------
// K1 (MFMA rewrite): conv(5x1,s2,SAME)+bias+relu+LN(32) -> bf16 hi/lo Xc
// (pre-swizzled 16B chunks, identical layout to rounds 2-4), xsp partials.
// Conv as GEMM: D[f, c] = sum_k W~[k, f] * Xwin[k, c], K = 40 (pad 48->64),
// k = kt*8+fi; bias folded in at k=40 (B row == 1.0; exact under hi/lo).
// mfma_f32_16x16x32_bf16, layout verified end-to-end by k4 (absmax 0):
//   A row=lane&15 (m=f), kchunk=lane>>4;  B col=lane&15 (n=c), kchunk=lane>>4;
//   D col=lane&15 (c), row=4*(lane>>4)+reg (f).
// Split products: WhBh + WhBl + WlBh (WlBl ~2^-18, dropped).
// Block 256 = 4 waves: wave w -> chalf=w&1 (32 c), rng=w>>1 (16 t2).
// Grid (32 t2-tiles, 32 b).  Weights live in 32 VGPRs (no s_load stream).
// ---------------------------------------------------------------------------
__global__ __launch_bounds__(256, 4) void k1_conv_ln(
    const float* __restrict__ X, const float* __restrict__ Wc,
    const float* __restrict__ bc, const float* __restrict__ g1,
    const float* __restrict__ be1, u16* __restrict__ Xch,
    u16* __restrict__ Xcl, float* __restrict__ xsp)
{
  __shared__ float xred[4][1056];   // [wave][(nt*16+cl)*33 + f], 16.9 KB
  const int tid = threadIdx.x;
  const int w = tid >> 6, lane = tid & 63;
  const int q = lane >> 4, cl = lane & 15;
  const int chalf = w & 1, rng = w >> 1;
  const int b = blockIdx.y, tile = blockIdx.x;
  const int cbase = chalf * 32;

  // ---- constant A-frags (weights; bias row at k=40), hi/lo split ----
  bf16x8 Wh[2][2], Wl[2][2];        // [s][mt]
#pragma unroll
  for (int s = 0; s < 2; ++s)
#pragma unroll
    for (int mt = 0; mt < 2; ++mt) {
      const int f = mt * 16 + cl;
      float x8[8];
#pragma unroll
      for (int j = 0; j < 8; ++j) {
        float wv;
        if (s == 0) {
          wv = Wc[(q * 8 + j) * 32 + f];          // k = q*8+j in [0,32)
        } else {
          wv = 0.f;
          if (q == 0) wv = Wc[(32 + j) * 32 + f]; // k = 32..39 (kt=4)
          if (q == 1 && j == 0) wv = bc[f];       // k = 40: bias row
        }
        x8[j] = wv;
      }
      unsigned hu[4], lu[4];
#pragma unroll
      for (int p = 0; p < 4; ++p) {
        const float a0 = x8[2*p], a1 = x8[2*p+1];
        hu[p] = bfpack(a0, a1);
        lu[p] = bfpack(a0 - bft(a0), a1 - bft(a1));
      }
      uint4 hv = make_uint4(hu[0], hu[1], hu[2], hu[3]);
      uint4 lv = make_uint4(lu[0], lu[1], lu[2], lu[3]);
      Wh[s][mt] = *(bf16x8*)&hv;
      Wl[s][mt] = *(bf16x8*)&lv;
    }

  // per-lane LN constants: f = mt*16 + 4q + r
  float g1r[2][4], be1r[2][4];
#pragma unroll
  for (int mt = 0; mt < 2; ++mt)
#pragma unroll
    for (int r = 0; r < 4; ++r) {
      const int f = mt * 16 + 4 * q + r;
      g1r[mt][r] = g1[f];
      be1r[mt][r] = be1[f];
    }

  float sacc[2][2][4];              // [mt][nt][r] running xsp partial
#pragma unroll
  for (int mt = 0; mt < 2; ++mt)
#pragma unroll
    for (int nt = 0; nt < 2; ++nt)
#pragma unroll
      for (int r = 0; r < 4; ++r) sacc[mt][nt][r] = 0.f;

  const float* Xb = X + (size_t)b * T_ * C_ * FI_;

#pragma unroll 1
  for (int it = 0; it < 16; ++it) {
    const int t2 = tile * 32 + rng * 16 + it;
    f32x4 acc[2][2];
#pragma unroll
    for (int mt = 0; mt < 2; ++mt)
#pragma unroll
      for (int nt = 0; nt < 2; ++nt) acc[mt][nt] = (f32x4){0.f,0.f,0.f,0.f};

#pragma unroll
    for (int nt = 0; nt < 2; ++nt) {
      const int c = cbase + nt * 16 + cl;
      const float* Xbc = Xb + (size_t)c * FI_;
      bf16x8 Bh[2], Bl[2];
      // s = 0: k = q*8+j -> kt=q, row = 2t2+q-1
      {
        const int row = 2 * t2 + q - 1;
        const bool ok = (row >= 0) && (row < T_);
        const int rc = row < 0 ? 0 : (row > T_ - 1 ? T_ - 1 : row);
        const float* p = Xbc + (size_t)rc * (C_ * FI_);
        const float4 xa = *(const float4*)p;
        const float4 xb2 = *(const float4*)(p + 4);
        float x8[8] = {xa.x, xa.y, xa.z, xa.w, xb2.x, xb2.y, xb2.z, xb2.w};
#pragma unroll
        for (int j = 0; j < 8; ++j) x8[j] = ok ? x8[j] : 0.f;
        unsigned hu[4], lu[4];
#pragma unroll
        for (int p2 = 0; p2 < 4; ++p2) {
          const float a0 = x8[2*p2], a1 = x8[2*p2+1];
          hu[p2] = bfpack(a0, a1);
          lu[p2] = bfpack(a0 - bft(a0), a1 - bft(a1));
        }
        uint4 hv = make_uint4(hu[0], hu[1], hu[2], hu[3]);
        uint4 lv = make_uint4(lu[0], lu[1], lu[2], lu[3]);
        Bh[0] = *(bf16x8*)&hv; Bl[0] = *(bf16x8*)&lv;
      }
      // s = 1: q=0 -> kt=4 row 2t2+3; q=1 j=0 -> 1.0 (bias); else 0
      {
        const int row = 2 * t2 + 3;
        const bool ok = (q == 0) && (row < T_);
        const int rc = row > T_ - 1 ? T_ - 1 : row;
        const float* p = Xbc + (size_t)rc * (C_ * FI_);
        const float4 xa = *(const float4*)p;
        const float4 xb2 = *(const float4*)(p + 4);
        float x8[8] = {xa.x, xa.y, xa.z, xa.w, xb2.x, xb2.y, xb2.z, xb2.w};
#pragma unroll
        for (int j = 0; j < 8; ++j) x8[j] = ok ? x8[j] : 0.f;
        unsigned hu[4], lu[4];
#pragma unroll
        for (int p2 = 0; p2 < 4; ++p2) {
          const float a0 = x8[2*p2], a1 = x8[2*p2+1];
          hu[p2] = bfpack(a0, a1);
          lu[p2] = bfpack(a0 - bft(a0), a1 - bft(a1));
        }
        uint4 hv = make_uint4(hu[0], hu[1], hu[2], hu[3]);
        uint4 lv = make_uint4(lu[0], lu[1], lu[2], lu[3]);
        bf16x8 bh = *(bf16x8*)&hv, bl = *(bf16x8*)&lv;
        if (q == 1) bh[0] = (short)0x3F80;   // bf16(1.0) at k=40
        Bh[1] = bh; Bl[1] = bl;
      }
      // 12 MFMAs for this nt
#pragma unroll
      for (int mt = 0; mt < 2; ++mt)
#pragma unroll
        for (int s = 0; s < 2; ++s) {
          acc[mt][nt] = __builtin_amdgcn_mfma_f32_16x16x32_bf16(Wh[s][mt], Bh[s], acc[mt][nt], 0, 0, 0);
          acc[mt][nt] = __builtin_amdgcn_mfma_f32_16x16x32_bf16(Wh[s][mt], Bl[s], acc[mt][nt], 0, 0, 0);
          acc[mt][nt] = __builtin_amdgcn_mfma_f32_16x16x32_bf16(Wl[s][mt], Bh[s], acc[mt][nt], 0, 0, 0);
        }
    }

    // epilogue: relu + LN(32 f) per c; c = lane&15 per nt, f spread over q,regs
#pragma unroll
    for (int nt = 0; nt < 2; ++nt) {
      float v[2][4];
      float s1 = 0.f, s2 = 0.f;
#pragma unroll
      for (int mt = 0; mt < 2; ++mt)
#pragma unroll
        for (int r = 0; r < 4; ++r) {
          const float vv = fmaxf(acc[mt][nt][r], 0.f);
          v[mt][r] = vv; s1 += vv; s2 = fmaf(vv, vv, s2);
        }
      s1 += __shfl_xor(s1, 16); s2 += __shfl_xor(s2, 16);
      s1 += __shfl_xor(s1, 32); s2 += __shfl_xor(s2, 32);
      const float mu = s1 * (1.f / 32.f);
      const float var = s2 * (1.f / 32.f) - mu * mu;
      const float rs = rsqrtf(var + 1e-6f);
      const int c = cbase + nt * 16 + cl;
      const size_t obase = ((size_t)(b * T2_ + t2) * C_ + c) * 32;
#pragma unroll
      for (int mt = 0; mt < 2; ++mt) {
        float y[4];
#pragma unroll
        for (int r = 0; r < 4; ++r) {
          y[r] = (v[mt][r] - mu) * rs * g1r[mt][r] + be1r[mt][r];
          sacc[mt][nt][r] += y[r];
        }
        const unsigned h0 = bfpack(y[0], y[1]), h1 = bfpack(y[2], y[3]);
        const unsigned l0 = bfpack(y[0] - bft(y[0]), y[1] - bft(y[1]));
        const unsigned l1 = bfpack(y[2] - bft(y[2]), y[3] - bft(y[3]));
        const int g = 2 * mt + (q >> 1);
        const int pos = ((g ^ (t2 & 3)) * 8) + (q & 1) * 4;
        *(uint2*)(Xch + obase + pos) = make_uint2(h0, h1);
        *(uint2*)(Xcl + obase + pos) = make_uint2(l0, l1);
      }
    }
  }

  // xsp: cross-wave (rng) reduce via LDS, then write f32 partials
#pragma unroll
  for (int mt = 0; mt < 2; ++mt)
#pragma unroll
    for (int nt = 0; nt < 2; ++nt)
#pragma unroll
      for (int r = 0; r < 4; ++r)
        xred[w][(nt * 16 + cl) * 33 + mt * 16 + 4 * q + r] = sacc[mt][nt][r];
  __syncthreads();
  if (w < 2) {
#pragma unroll
    for (int mt = 0; mt < 2; ++mt)
#pragma unroll
      for (int nt = 0; nt < 2; ++nt)
#pragma unroll
        for (int r = 0; r < 4; ++r) {
          const int idx = (nt * 16 + cl) * 33 + mt * 16 + 4 * q + r;
          const float vv = xred[w][idx] + xred[w + 2][idx];
          xsp[((size_t)b * 32 + tile) * 2048 +
              (size_t)(w * 32 + nt * 16 + cl) * 32 + mt * 16 + 4 * q + r] = vv;
        }
  }
}

// ---------------------------------------------------------------------------
// K2: x_spat reduce, q/k, adj=softmax, ca=sigmoid; A'[c][d] = ca[c]adj[c,d]+I
// ---------------------------------------------------------------------------
__global__ __launch_bounds__(256) void k2_graph(
    const float* __restrict__ xsp, const float* __restrict__ qw,
    const float* __restrict__ qb, const float* __restrict__ kw,
    const float* __restrict__ kb, const float* __restrict__ caw,
    const float* __restrict__ cab, float* __restrict__ Aout)
{
  __shared__ float xs[64 * 32];
  __shared__ float qs[64][32];
  __shared__ float ks[64][32];
  __shared__ float sc[64][64];
  __shared__ float cain[64];
  __shared__ float cav[64];
  const int tid = threadIdx.x;
  const int b = blockIdx.x;

  for (int idx = tid; idx < 2048; idx += 256) {
    float s = 0.f;
    for (int p = 0; p < 32; ++p) s += xsp[((size_t)b * 32 + p) * 2048 + idx];
    xs[idx] = s * (1.f / (float)T2_);
  }
  __syncthreads();

  if (tid < 64) {
    float s = 0.f;
#pragma unroll
    for (int f = 0; f < 32; ++f) s += xs[tid * 32 + f];
    cain[tid] = s * (1.f / 32.f);
  }
  {
    const int cc = tid >> 2, part = tid & 3;
    float aq[8], ak[8];
#pragma unroll
    for (int j = 0; j < 8; ++j) { aq[j] = qb[part*8+j]; ak[j] = kb[part*8+j]; }
    for (int f = 0; f < 32; ++f) {
      const float xv = xs[cc * 32 + f];
#pragma unroll
      for (int j = 0; j < 8; ++j) {
        aq[j] = fmaf(xv, qw[f * 32 + part*8+j], aq[j]);
        ak[j] = fmaf(xv, kw[f * 32 + part*8+j], ak[j]);
      }
    }
#pragma unroll
    for (int j = 0; j < 8; ++j) { qs[cc][part*8+j] = aq[j]; ks[cc][part*8+j] = ak[j]; }
  }
  __syncthreads();
  {
    const int cc = tid >> 2, part = tid & 3;
    for (int dd = part * 16; dd < part * 16 + 16; ++dd) {
      float s = 0.f;
#pragma unroll
      for (int e = 0; e < 32; ++e) s = fmaf(qs[cc][e], ks[dd][e], s);
      sc[cc][dd] = s * 0.1767766953f;
    }
  }
  __syncthreads();
  if (tid < 64) {
    const int cc = tid;
    float m = -1e30f;
    for (int d = 0; d < 64; ++d) m = fmaxf(m, sc[cc][d]);
    float sum = 0.f;
    for (int d = 0; d < 64; ++d) { float e = expf(sc[cc][d] - m); sc[cc][d] = e; sum += e; }
    const float inv = 1.f / sum;
    for (int d = 0; d < 64; ++d) sc[cc][d] *= inv;
    float a = cab[cc];
    for (int d = 0; d < 64; ++d) a = fmaf(cain[d], caw[d * 64 + cc], a);
    cav[cc] = 1.f / (1.f + expf(-a));
  }
  __syncthreads();
  for (int idx = tid; idx < 4096; idx += 256) {
    const int cc = idx >> 6, dd = idx & 63;
    Aout[(size_t)b * 4096 + idx] = cav[cc] * sc[cc][dd] + (cc == dd ? 1.f : 0.f);
  }
}

// ---------------------------------------------------------------------------
// K3: Weff_T[b][d][h][f] = sum_c A'[c][d] mixw[c*32+f][h], bf16 hi/lo,
// g^(h&3) chunk pre-swizzle.
// ---------------------------------------------------------------------------
__global__ __launch_bounds__(256) void k3_weff(
    const float* __restrict__ Aout, const float* __restrict__ mixw,
    u16* __restrict__ Wth, u16* __restrict__ Wtl)
{
  __shared__ float Ap[4096];   // A'[c][d]
  __shared__ float Ms[2048];   // [cc16][hl4][f32]
  const int tid = threadIdx.x;
  const int b = blockIdx.x >> 5, ht = blockIdx.x & 31;
  const int d = tid & 63, hl = tid >> 6;
  const int h0 = ht * 4;
  const float* Ab = Aout + (size_t)b * 4096;
#pragma unroll
  for (int l = 0; l < 16; ++l) Ap[tid + 256 * l] = Ab[tid + 256 * l];

  float acc[32];
#pragma unroll
  for (int j = 0; j < 32; ++j) acc[j] = 0.f;

  for (int c0 = 0; c0 < 64; c0 += 16) {
    __syncthreads();
    {
      const int i0 = tid * 8;
#pragma unroll
      for (int qd = 0; qd < 2; ++qd) {
        const int i = i0 + qd * 4;
        const int cc = i >> 7, f = (i >> 2) & 31;
        const float4 v = *(const float4*)&mixw[((size_t)((c0+cc)*32 + f))*128 + h0];
        float* mp = &Ms[cc * 128 + f];
        mp[0] = v.x; mp[32] = v.y; mp[64] = v.z; mp[96] = v.w;
      }
    }
    __syncthreads();
#pragma unroll 4
    for (int cc = 0; cc < 16; ++cc) {
      const float a = Ap[(c0 + cc) * 64 + d];
      const float* mrow = &Ms[cc * 128 + hl * 32];
#pragma unroll
      for (int fq = 0; fq < 8; ++fq) {
        const f32x4 m = *(const f32x4*)&mrow[fq * 4];
        acc[fq*4+0] = fmaf(a, m[0], acc[fq*4+0]);
        acc[fq*4+1] = fmaf(a, m[1], acc[fq*4+1]);
        acc[fq*4+2] = fmaf(a, m[2], acc[fq*4+2]);
        acc[fq*4+3] = fmaf(a, m[3], acc[fq*4+3]);
      }
    }
  }

  const int h = h0 + hl;
  const size_t obase = ((size_t)(b * 64 + d) * 128 + h) * 32;
#pragma unroll
  for (int g = 0; g < 4; ++g) {
    unsigned hq[4], lq[4];
#pragma unroll
    for (int jj = 0; jj < 4; ++jj) {
      const float ya = acc[8*g + 2*jj], yb = acc[8*g + 2*jj + 1];
      const float ha = bft(ya), hb = bft(yb);
      hq[jj] = (__float_as_uint(ha) >> 16) | (__float_as_uint(hb) & 0xffff0000u);
      lq[jj] = bfpack(ya - ha, yb - hb);
    }
    const int pg = (g ^ hl) * 8;   // h&3 == hl
    *(uint4*)(Wth + obase + pg) = make_uint4(hq[0], hq[1], hq[2], hq[3]);
    *(uint4*)(Wtl + obase + pg) = make_uint4(lq[0], lq[1], lq[2], lq[3]);
  }
}

// ---------------------------------------------------------------------------
// K4: Xm = LN2(relu(Xc @ Weff + mix_b)) via bf16-split MFMA (unchanged).
// ---------------------------------------------------------------------------
__global__ __launch_bounds__(256) void k4_gemm(
    const u16* __restrict__ Agh, const u16* __restrict__ Agl,
    const u16* __restrict__ Bgh, const u16* __restrict__ Bgl,
    const float* __restrict__ mixb, const float* __restrict__ g2,
    const float* __restrict__ be2, float* __restrict__ Xm)
{
  __shared__ __align__(16) u16 lds[2 * 12288];
  __shared__ float part[64 * 8];
  __shared__ float murs[128];

  const int tid = threadIdx.x;
  const int w = tid >> 6, lane = tid & 63;
  const int x = blockIdx.x;
  const int swz = (x & 7) * 64 + (x >> 3);
  const int b = swz >> 4, mt = swz & 15;
  const int m0 = mt * 64;

  f32x4 acc[4][2];
#pragma unroll
  for (int i = 0; i < 4; ++i)
#pragma unroll
    for (int j = 0; j < 2; ++j) acc[i][j] = (f32x4){0.f, 0.f, 0.f, 0.f};

  const int lrow = lane >> 2, lg = lane & 3;
  const size_t arow  = (size_t)(b * 1024 + m0 + w * 16 + lrow) * 2048 + lg * 8;
  const size_t brow0 = (size_t)b * 262144 + (size_t)(w * 16 + lrow) * 32 + lg * 8;
  const int dA = w * 512;

#define STAGE_K4(kt, buf) do {                                               \
    const int db_ = (buf) * 12288;                                           \
    glds16(Agh + arow + (size_t)(kt) * 32, &lds[db_ + dA]);                  \
    glds16(Agl + arow + (size_t)(kt) * 32, &lds[db_ + 2048 + dA]);           \
    glds16(Bgh + brow0 + (size_t)(kt) * 4096,        &lds[db_ + 4096 + dA]); \
    glds16(Bgh + brow0 + (size_t)(kt) * 4096 + 2048, &lds[db_ + 6144 + dA]); \
    glds16(Bgl + brow0 + (size_t)(kt) * 4096,        &lds[db_ + 8192 + dA]); \
    glds16(Bgl + brow0 + (size_t)(kt) * 4096 + 2048, &lds[db_ + 10240 + dA]);\
  } while (0)

  const int fa = (lane & 15) * 32 + (((lane >> 4) ^ (lane & 3)) * 8);

  int cur = 0;
  STAGE_K4(0, 0);
  __syncthreads();

  for (int kt = 0; kt < 64; ++kt) {
    if (kt < 63) STAGE_K4(kt + 1, cur ^ 1);
    const u16* base = &lds[cur * 12288];
    bf16x8 ah[4], al[4], bh[2], bl[2];
#pragma unroll
    for (int mf = 0; mf < 4; ++mf) {
      ah[mf] = *(const bf16x8*)(base + mf * 512 + fa);
      al[mf] = *(const bf16x8*)(base + 2048 + mf * 512 + fa);
    }
#pragma unroll
    for (int nf = 0; nf < 2; ++nf) {
      bh[nf] = *(const bf16x8*)(base + 4096 + w * 1024 + nf * 512 + fa);
      bl[nf] = *(const bf16x8*)(base + 8192 + w * 1024 + nf * 512 + fa);
    }
#pragma unroll
    for (int mf = 0; mf < 4; ++mf)
#pragma unroll
      for (int nf = 0; nf < 2; ++nf) {
        acc[mf][nf] = __builtin_amdgcn_mfma_f32_16x16x32_bf16(ah[mf], bh[nf], acc[mf][nf], 0, 0, 0);
        acc[mf][nf] = __builtin_amdgcn_mfma_f32_16x16x32_bf16(ah[mf], bl[nf], acc[mf][nf], 0, 0, 0);
        acc[mf][nf] = __builtin_amdgcn_mfma_f32_16x16x32_bf16(al[mf], bh[nf], acc[mf][nf], 0, 0, 0);
      }
    __syncthreads();
    cur ^= 1;
  }
#undef STAGE_K4

  const int c0 = w * 32 + (lane & 15);
  const float bias0 = mixb[c0], bias1 = mixb[c0 + 16];
#pragma unroll
  for (int mf = 0; mf < 4; ++mf)
#pragma unroll
    for (int r = 0; r < 4; ++r) {
      float v0 = fmaxf(acc[mf][0][r] + bias0, 0.f);
      float v1 = fmaxf(acc[mf][1][r] + bias1, 0.f);
      acc[mf][0][r] = v0; acc[mf][1][r] = v1;
      float s1 = v0 + v1, s2 = v0 * v0 + v1 * v1;
      s1 += __shfl_xor(s1, 1);  s2 += __shfl_xor(s2, 1);
      s1 += __shfl_xor(s1, 2);  s2 += __shfl_xor(s2, 2);
      s1 += __shfl_xor(s1, 4);  s2 += __shfl_xor(s2, 4);
      s1 += __shfl_xor(s1, 8);  s2 += __shfl_xor(s2, 8);
      if ((lane & 15) == 0) {
        const int row = mf * 16 + (lane >> 4) * 4 + r;
        part[row * 8 + w * 2] = s1;
        part[row * 8 + w * 2 + 1] = s2;
      }
    }
  __syncthreads();
  if (tid < 64) {
    const float s1 = part[tid*8] + part[tid*8+2] + part[tid*8+4] + part[tid*8+6];
    const float s2 = part[tid*8+1] + part[tid*8+3] + part[tid*8+5] + part[tid*8+7];
    const float mu = s1 * (1.f / 128.f);
    const float var = s2 * (1.f / 128.f) - mu * mu;
    murs[tid * 2] = mu;
    murs[tid * 2 + 1] = rsqrtf(var + 1e-6f);
  }
  __syncthreads();
  const float g20 = g2[c0], g21 = g2[c0 + 16];
  const float b20 = be2[c0], b21 = be2[c0 + 16];
#pragma unroll
  for (int mf = 0; mf < 4; ++mf)
#pragma unroll
    for (int r = 0; r < 4; ++r) {
      const int row = mf * 16 + (lane >> 4) * 4 + r;
      const float mu = murs[row * 2], rs = murs[row * 2 + 1];
      float* op = Xm + (size_t)(b * 1024 + m0 + row) * 128;
      op[c0]      = (acc[mf][0][r] - mu) * rs * g20 + b20;
      op[c0 + 16] = (acc[mf][1][r] - mu) * rs * g21 + b21;
    }
}

// ---------------------------------------------------------------------------
// K5: LIF scan, 4096 chains spread over 64 blocks
// ---------------------------------------------------------------------------
__global__ __launch_bounds__(64) void k5_lif(
    const float* __restrict__ Xm, const float* __restrict__ dl,
    float* __restrict__ fs)
{
  const int id = blockIdx.x * 64 + threadIdx.x;
  const int b = id >> 7, h = id & 127;
  const float decay = 1.f / (1.f + expf(-dl[h]));
  float mem = 0.f, cnt = 0.f;
  const float* p = Xm + (size_t)b * T2_ * H_ + h;
#pragma unroll 16
  for (int t = 0; t < T2_; ++t) {
    const float xv = p[(size_t)t * H_];
    mem = fmaf(mem, decay, xv);
    const float sp = ((mem - 0.5f) > 0.f) ? 1.f : 0.f;
    cnt += sp;
    mem -= 0.5f * sp;
  }
  fs[b * H_ + h] = cnt;
}

// ---------------------------------------------------------------------------
// K6: head
// ---------------------------------------------------------------------------
__global__ __launch_bounds__(256) void k6_head(
    const float* __restrict__ fs, const float* __restrict__ fcw,
    const float* __restrict__ fcb, const float* __restrict__ ow,
    const float* __restrict__ ob, float* __restrict__ out)
{
  __shared__ float f[32 * 128];
  __shared__ float fr[32 * 128];
  __shared__ float red[256];
  const int tid = threadIdx.x;
  float tot = 0.f;
  for (int idx = tid; idx < 4096; idx += 256) {
    const float v = fs[idx];
    f[idx] = v * (1.f / (float)T2_);
    tot += v;
  }
  red[tid] = tot;
  __syncthreads();
  for (int s = 128; s > 0; s >>= 1) {
    if (tid < s) red[tid] += red[tid + s];
    __syncthreads();
  }
  {
    const int bb = tid >> 3, og = tid & 7;
    float a[16];
#pragma unroll
    for (int j = 0; j < 16; ++j) a[j] = fcb[og * 16 + j];
    for (int hh = 0; hh < 128; ++hh) {
      const float fv = f[bb * 128 + hh];
#pragma unroll
      for (int j = 0; j < 16; ++j)
        a[j] = fmaf(fv, fcw[hh * 128 + og * 16 + j], a[j]);
    }
#pragma unroll
    for (int j = 0; j < 16; ++j) fr[bb * 128 + og * 16 + j] = fmaxf(a[j], 0.f);
  }
  __syncthreads();
  if (tid < 128) {
    const int bb = tid >> 2, cls = tid & 3;
    float a = ob[cls];
    for (int o = 0; o < 128; ++o) a = fmaf(fr[bb * 128 + o], ow[o * 4 + cls], a);
    out[bb * 4 + cls] = a;
  }
  if (tid == 0) out[128] = red[0] * (1.f / (4096.f * 1024.f));
}

// ---------------------------------------------------------------------------
extern "C" void kernel_launch(void* const* d_in, const int* in_sizes, int n_in,
                              void* d_out, int out_size, void* d_ws, size_t ws_size,
                              hipStream_t stream) {
  const float* X     = (const float*)d_in[0];
  const float* convw = (const float*)d_in[1];
  const float* convb = (const float*)d_in[2];
  const float* ln1s  = (const float*)d_in[3];
  const float* ln1b  = (const float*)d_in[4];
  const float* qw    = (const float*)d_in[5];
  const float* qb    = (const float*)d_in[6];
  const float* kw    = (const float*)d_in[7];
  const float* kb    = (const float*)d_in[8];
  const float* caw   = (const float*)d_in[9];
  const float* cab   = (const float*)d_in[10];
  const float* mixw  = (const float*)d_in[11];
  const float* mixb  = (const float*)d_in[12];
  const float* ln2s  = (const float*)d_in[13];
  const float* ln2b  = (const float*)d_in[14];
  const float* dl    = (const float*)d_in[15];
  const float* fcw   = (const float*)d_in[16];
  const float* fcb   = (const float*)d_in[17];
  const float* outw  = (const float*)d_in[18];
  const float* outb  = (const float*)d_in[19];

  float* ws  = (float*)d_ws;
  u16* Xch   = (u16*)(ws + OFF_XCH);
  u16* Xcl   = (u16*)(ws + OFF_XCL);
  u16* Wth   = (u16*)(ws + OFF_WTH);
  u16* Wtl   = (u16*)(ws + OFF_WTL);
  float* xsp = ws + OFF_XSP;
  float* Aou = ws + OFF_A;
  float* Xm  = ws + OFF_XM;
  float* fs  = ws + OFF_A;   // reuse (A' dead after k3)

  dim3 g1(32, 32);
  k1_conv_ln<<<g1, 256, 0, stream>>>(X, convw, convb, ln1s, ln1b, Xch, Xcl, xsp);
  k2_graph<<<32, 256, 0, stream>>>(xsp, qw, qb, kw, kb, caw, cab, Aou);
  k3_weff<<<1024, 256, 0, stream>>>(Aou, mixw, Wth, Wtl);
  k4_gemm<<<512, 256, 0, stream>>>(Xch, Xcl, Wth, Wtl, mixb, ln2s, ln2b, Xm);
  k5_lif<<<64, 64, 0, stream>>>(Xm, dl, fs);
  k6_head<<<1, 256, 0, stream>>>(fs, fcw, fcb, outw, outb, (float*)d_out);
}

// Round 6
// 314.994 us; speedup vs baseline: 2.4182x; 1.2315x over previous
//
#include <hip/hip_runtime.h>
#include <math.h>

#define B_    32
#define T_    2048
#define T2_   1024
#define C_    64
#define FI_   8
#define FO_   32
#define K_    2048   // C_*CONV_F
#define H_    128

typedef unsigned short u16;
typedef short bf16x8 __attribute__((ext_vector_type(8)));
typedef float f32x4 __attribute__((ext_vector_type(4)));

// workspace offsets (in FLOAT units) - Xc eliminated this round; offsets kept
#define OFF_WTH  ((size_t)67108864)   // bf16 hi Weff_T
#define OFF_WTL  ((size_t)71303168)
#define OFF_XSP  ((size_t)75497472)   // 32*32*2048 f32
#define OFF_A    ((size_t)77594624)   // 32*64*64 f32 (A'); reused later for fs
#define OFF_XM   ((size_t)77725696)   // 32*1024*128 f32

// ---- bf16 helpers --------------------------------------------------------
__device__ __forceinline__ float bft(float x) {  // value of bf16-rounded x
  unsigned u = __float_as_uint(x);
  u = (u + 0x7fffu + ((u >> 16) & 1u)) & 0xffff0000u;
  return __uint_as_float(u);
}
__device__ __forceinline__ unsigned bfpack(float a, float b) { // manual RTNE
  unsigned ua = __float_as_uint(a); ua = (ua + 0x7fffu + ((ua >> 16) & 1u)) >> 16;
  unsigned ub = __float_as_uint(b); ub = (ub + 0x7fffu + ((ub >> 16) & 1u)) & 0xffff0000u;
  return ua | ub;
}
// HW packed convert (RTNE): lo16 = bf16(a), hi16 = bf16(b) - 1 instruction
__device__ __forceinline__ unsigned cvtpk(float a, float b) {
  unsigned r;
  asm("v_cvt_pk_bf16_f32 %0, %1, %2" : "=v"(r) : "v"(a), "v"(b));
  return r;
}

// async global->LDS, 16B per lane; LDS dest must be wave-uniform base
__device__ __forceinline__ void glds16(const u16* g, u16* l) {
  auto gp = reinterpret_cast<const __attribute__((address_space(1))) unsigned int*>(
      reinterpret_cast<uintptr_t>(g));
  auto lp = reinterpret_cast<__attribute__((address_space(3))) unsigned int*>(
      reinterpret_cast<uintptr_t>(l));
  __builtin_amdgcn_global_load_lds(gp, lp, 16, 0, 0);
}

// ---------------------------------------------------------------------------
// K1lite: conv(5x1,s2,SAME)+bias+relu+LN(32) -> ONLY xsp mean partials.
// (Xc is NOT materialized any more - k4 recomputes it in-register.)
// Same MFMA structure as round-5 k1; pack of conv inputs via cvt_pk.
// ---------------------------------------------------------------------------
__global__ __launch_bounds__(256, 4) void k1_conv_ln(
    const float* __restrict__ X, const float* __restrict__ Wc,
    const float* __restrict__ bc, const float* __restrict__ g1,
    const float* __restrict__ be1, float* __restrict__ xsp)
{
  __shared__ float xred[4][1056];
  const int tid = threadIdx.x;
  const int w = tid >> 6, lane = tid & 63;
  const int q = lane >> 4, cl = lane & 15;
  const int chalf = w & 1, rng = w >> 1;
  const int b = blockIdx.y, tile = blockIdx.x;
  const int cbase = chalf * 32;

  // constant A-frags (weights; bias row at k=40), hi/lo split
  bf16x8 Wh[2][2], Wl[2][2];
#pragma unroll
  for (int s = 0; s < 2; ++s)
#pragma unroll
    for (int mt = 0; mt < 2; ++mt) {
      const int f = mt * 16 + cl;
      float x8[8];
#pragma unroll
      for (int j = 0; j < 8; ++j) {
        float wv;
        if (s == 0) {
          wv = Wc[(q * 8 + j) * 32 + f];
        } else {
          wv = 0.f;
          if (q == 0) wv = Wc[(32 + j) * 32 + f];
          if (q == 1 && j == 0) wv = bc[f];
        }
        x8[j] = wv;
      }
      unsigned hu[4], lu[4];
#pragma unroll
      for (int p = 0; p < 4; ++p) {
        const float a0 = x8[2*p], a1 = x8[2*p+1];
        hu[p] = bfpack(a0, a1);
        lu[p] = bfpack(a0 - bft(a0), a1 - bft(a1));
      }
      uint4 hv = make_uint4(hu[0], hu[1], hu[2], hu[3]);
      uint4 lv = make_uint4(lu[0], lu[1], lu[2], lu[3]);
      Wh[s][mt] = *(bf16x8*)&hv;
      Wl[s][mt] = *(bf16x8*)&lv;
    }

  float g1r[2][4], be1r[2][4];
#pragma unroll
  for (int mt = 0; mt < 2; ++mt)
#pragma unroll
    for (int r = 0; r < 4; ++r) {
      const int f = mt * 16 + 4 * q + r;
      g1r[mt][r] = g1[f];
      be1r[mt][r] = be1[f];
    }

  float sacc[2][2][4];
#pragma unroll
  for (int mt = 0; mt < 2; ++mt)
#pragma unroll
    for (int nt = 0; nt < 2; ++nt)
#pragma unroll
      for (int r = 0; r < 4; ++r) sacc[mt][nt][r] = 0.f;

  const float* Xb = X + (size_t)b * T_ * C_ * FI_;

#pragma unroll 1
  for (int it = 0; it < 16; ++it) {
    const int t2 = tile * 32 + rng * 16 + it;
    f32x4 acc[2][2];
#pragma unroll
    for (int mt = 0; mt < 2; ++mt)
#pragma unroll
      for (int nt = 0; nt < 2; ++nt) acc[mt][nt] = (f32x4){0.f,0.f,0.f,0.f};

#pragma unroll
    for (int nt = 0; nt < 2; ++nt) {
      const int c = cbase + nt * 16 + cl;
      const float* Xbc = Xb + (size_t)c * FI_;
      bf16x8 Bh[2], Bl[2];
      // s = 0: k = q*8+j -> kt=q, row = 2t2+q-1
      {
        const int row = 2 * t2 + q - 1;
        const bool ok = (row >= 0) && (row < T_);
        const int rc = ok ? row : 0;
        const float* p = Xbc + (size_t)rc * (C_ * FI_);
        const float4 xa = *(const float4*)p;
        const float4 xb2 = *(const float4*)(p + 4);
        float x8[8] = {xa.x, xa.y, xa.z, xa.w, xb2.x, xb2.y, xb2.z, xb2.w};
#pragma unroll
        for (int j = 0; j < 8; ++j) x8[j] = ok ? x8[j] : 0.f;
        unsigned hu[4], lu[4];
#pragma unroll
        for (int p2 = 0; p2 < 4; ++p2) {
          const float a0 = x8[2*p2], a1 = x8[2*p2+1];
          const unsigned ph = cvtpk(a0, a1);
          hu[p2] = ph;
          const float f0 = __uint_as_float(ph << 16);
          const float f1 = __uint_as_float(ph & 0xffff0000u);
          lu[p2] = cvtpk(a0 - f0, a1 - f1);
        }
        uint4 hv = make_uint4(hu[0], hu[1], hu[2], hu[3]);
        uint4 lv = make_uint4(lu[0], lu[1], lu[2], lu[3]);
        Bh[0] = *(bf16x8*)&hv; Bl[0] = *(bf16x8*)&lv;
      }
      // s = 1: q=0 -> kt=4 row 2t2+3; q=1 j=0 -> 1.0 (bias); else 0
      {
        const int row = 2 * t2 + 3;
        const bool ok = (q == 0) && (row < T_);
        const int rc = ok ? row : 0;
        const float* p = Xbc + (size_t)rc * (C_ * FI_);
        const float4 xa = *(const float4*)p;
        const float4 xb2 = *(const float4*)(p + 4);
        float x8[8] = {xa.x, xa.y, xa.z, xa.w, xb2.x, xb2.y, xb2.z, xb2.w};
#pragma unroll
        for (int j = 0; j < 8; ++j) x8[j] = ok ? x8[j] : 0.f;
        unsigned hu[4], lu[4];
#pragma unroll
        for (int p2 = 0; p2 < 4; ++p2) {
          const float a0 = x8[2*p2], a1 = x8[2*p2+1];
          const unsigned ph = cvtpk(a0, a1);
          hu[p2] = ph;
          const float f0 = __uint_as_float(ph << 16);
          const float f1 = __uint_as_float(ph & 0xffff0000u);
          lu[p2] = cvtpk(a0 - f0, a1 - f1);
        }
        uint4 hv = make_uint4(hu[0], hu[1], hu[2], hu[3]);
        uint4 lv = make_uint4(lu[0], lu[1], lu[2], lu[3]);
        bf16x8 bh = *(bf16x8*)&hv, bl = *(bf16x8*)&lv;
        if (q == 1) bh[0] = (short)0x3F80;
        Bh[1] = bh; Bl[1] = bl;
      }
#pragma unroll
      for (int mt = 0; mt < 2; ++mt)
#pragma unroll
        for (int s = 0; s < 2; ++s) {
          acc[mt][nt] = __builtin_amdgcn_mfma_f32_16x16x32_bf16(Wh[s][mt], Bh[s], acc[mt][nt], 0, 0, 0);
          acc[mt][nt] = __builtin_amdgcn_mfma_f32_16x16x32_bf16(Wh[s][mt], Bl[s], acc[mt][nt], 0, 0, 0);
          acc[mt][nt] = __builtin_amdgcn_mfma_f32_16x16x32_bf16(Wl[s][mt], Bh[s], acc[mt][nt], 0, 0, 0);
        }
    }

    // relu + LN(32) -> accumulate mean only
#pragma unroll
    for (int nt = 0; nt < 2; ++nt) {
      float v[2][4];
      float s1 = 0.f, s2 = 0.f;
#pragma unroll
      for (int mt = 0; mt < 2; ++mt)
#pragma unroll
        for (int r = 0; r < 4; ++r) {
          const float vv = fmaxf(acc[mt][nt][r], 0.f);
          v[mt][r] = vv; s1 += vv; s2 = fmaf(vv, vv, s2);
        }
      s1 += __shfl_xor(s1, 16); s2 += __shfl_xor(s2, 16);
      s1 += __shfl_xor(s1, 32); s2 += __shfl_xor(s2, 32);
      const float mu = s1 * (1.f / 32.f);
      const float var = s2 * (1.f / 32.f) - mu * mu;
      const float rs = rsqrtf(var + 1e-6f);
#pragma unroll
      for (int mt = 0; mt < 2; ++mt)
#pragma unroll
        for (int r = 0; r < 4; ++r)
          sacc[mt][nt][r] += (v[mt][r] - mu) * rs * g1r[mt][r] + be1r[mt][r];
    }
  }

  // cross-wave (rng) reduce via LDS, write xsp partials
#pragma unroll
  for (int mt = 0; mt < 2; ++mt)
#pragma unroll
    for (int nt = 0; nt < 2; ++nt)
#pragma unroll
      for (int r = 0; r < 4; ++r)
        xred[w][(nt * 16 + cl) * 33 + mt * 16 + 4 * q + r] = sacc[mt][nt][r];
  __syncthreads();
  if (w < 2) {
#pragma unroll
    for (int mt = 0; mt < 2; ++mt)
#pragma unroll
      for (int nt = 0; nt < 2; ++nt)
#pragma unroll
        for (int r = 0; r < 4; ++r) {
          const int idx = (nt * 16 + cl) * 33 + mt * 16 + 4 * q + r;
          const float vv = xred[w][idx] + xred[w + 2][idx];
          xsp[((size_t)b * 32 + tile) * 2048 +
              (size_t)(w * 32 + nt * 16 + cl) * 32 + mt * 16 + 4 * q + r] = vv;
        }
  }
}

// ---------------------------------------------------------------------------
// K2: x_spat reduce, q/k, adj=softmax, ca=sigmoid; A'[c][d] = ca[c]adj[c,d]+I
// ---------------------------------------------------------------------------
__global__ __launch_bounds__(256) void k2_graph(
    const float* __restrict__ xsp, const float* __restrict__ qw,
    const float* __restrict__ qb, const float* __restrict__ kw,
    const float* __restrict__ kb, const float* __restrict__ caw,
    const float* __restrict__ cab, float* __restrict__ Aout)
{
  __shared__ float xs[64 * 32];
  __shared__ float qs[64][32];
  __shared__ float ks[64][32];
  __shared__ float sc[64][64];
  __shared__ float cain[64];
  __shared__ float cav[64];
  const int tid = threadIdx.x;
  const int b = blockIdx.x;

  for (int idx = tid; idx < 2048; idx += 256) {
    float s = 0.f;
    for (int p = 0; p < 32; ++p) s += xsp[((size_t)b * 32 + p) * 2048 + idx];
    xs[idx] = s * (1.f / (float)T2_);
  }
  __syncthreads();

  if (tid < 64) {
    float s = 0.f;
#pragma unroll
    for (int f = 0; f < 32; ++f) s += xs[tid * 32 + f];
    cain[tid] = s * (1.f / 32.f);
  }
  {
    const int cc = tid >> 2, part = tid & 3;
    float aq[8], ak[8];
#pragma unroll
    for (int j = 0; j < 8; ++j) { aq[j] = qb[part*8+j]; ak[j] = kb[part*8+j]; }
    for (int f = 0; f < 32; ++f) {
      const float xv = xs[cc * 32 + f];
#pragma unroll
      for (int j = 0; j < 8; ++j) {
        aq[j] = fmaf(xv, qw[f * 32 + part*8+j], aq[j]);
        ak[j] = fmaf(xv, kw[f * 32 + part*8+j], ak[j]);
      }
    }
#pragma unroll
    for (int j = 0; j < 8; ++j) { qs[cc][part*8+j] = aq[j]; ks[cc][part*8+j] = ak[j]; }
  }
  __syncthreads();
  {
    const int cc = tid >> 2, part = tid & 3;
    for (int dd = part * 16; dd < part * 16 + 16; ++dd) {
      float s = 0.f;
#pragma unroll
      for (int e = 0; e < 32; ++e) s = fmaf(qs[cc][e], ks[dd][e], s);
      sc[cc][dd] = s * 0.1767766953f;
    }
  }
  __syncthreads();
  if (tid < 64) {
    const int cc = tid;
    float m = -1e30f;
    for (int d = 0; d < 64; ++d) m = fmaxf(m, sc[cc][d]);
    float sum = 0.f;
    for (int d = 0; d < 64; ++d) { float e = expf(sc[cc][d] - m); sc[cc][d] = e; sum += e; }
    const float inv = 1.f / sum;
    for (int d = 0; d < 64; ++d) sc[cc][d] *= inv;
    float a = cab[cc];
    for (int d = 0; d < 64; ++d) a = fmaf(cain[d], caw[d * 64 + cc], a);
    cav[cc] = 1.f / (1.f + expf(-a));
  }
  __syncthreads();
  for (int idx = tid; idx < 4096; idx += 256) {
    const int cc = idx >> 6, dd = idx & 63;
    Aout[(size_t)b * 4096 + idx] = cav[cc] * sc[cc][dd] + (cc == dd ? 1.f : 0.f);
  }
}

// ---------------------------------------------------------------------------
// K3: Weff_T[b][d][h][f] = sum_c A'[c][d] mixw[c*32+f][h], bf16 hi/lo,
// g^(h&3) chunk pre-swizzle.
// ---------------------------------------------------------------------------
__global__ __launch_bounds__(256) void k3_weff(
    const float* __restrict__ Aout, const float* __restrict__ mixw,
    u16* __restrict__ Wth, u16* __restrict__ Wtl)
{
  __shared__ float Ap[4096];
  __shared__ float Ms[2048];
  const int tid = threadIdx.x;
  const int b = blockIdx.x >> 5, ht = blockIdx.x & 31;
  const int d = tid & 63, hl = tid >> 6;
  const int h0 = ht * 4;
  const float* Ab = Aout + (size_t)b * 4096;
#pragma unroll
  for (int l = 0; l < 16; ++l) Ap[tid + 256 * l] = Ab[tid + 256 * l];

  float acc[32];
#pragma unroll
  for (int j = 0; j < 32; ++j) acc[j] = 0.f;

  for (int c0 = 0; c0 < 64; c0 += 16) {
    __syncthreads();
    {
      const int i0 = tid * 8;
#pragma unroll
      for (int qd = 0; qd < 2; ++qd) {
        const int i = i0 + qd * 4;
        const int cc = i >> 7, f = (i >> 2) & 31;
        const float4 v = *(const float4*)&mixw[((size_t)((c0+cc)*32 + f))*128 + h0];
        float* mp = &Ms[cc * 128 + f];
        mp[0] = v.x; mp[32] = v.y; mp[64] = v.z; mp[96] = v.w;
      }
    }
    __syncthreads();
#pragma unroll 4
    for (int cc = 0; cc < 16; ++cc) {
      const float a = Ap[(c0 + cc) * 64 + d];
      const float* mrow = &Ms[cc * 128 + hl * 32];
#pragma unroll
      for (int fq = 0; fq < 8; ++fq) {
        const f32x4 m = *(const f32x4*)&mrow[fq * 4];
        acc[fq*4+0] = fmaf(a, m[0], acc[fq*4+0]);
        acc[fq*4+1] = fmaf(a, m[1], acc[fq*4+1]);
        acc[fq*4+2] = fmaf(a, m[2], acc[fq*4+2]);
        acc[fq*4+3] = fmaf(a, m[3], acc[fq*4+3]);
      }
    }
  }

  const int h = h0 + hl;
  const size_t obase = ((size_t)(b * 64 + d) * 128 + h) * 32;
#pragma unroll
  for (int g = 0; g < 4; ++g) {
    unsigned hq[4], lq[4];
#pragma unroll
    for (int jj = 0; jj < 4; ++jj) {
      const float ya = acc[8*g + 2*jj], yb = acc[8*g + 2*jj + 1];
      const float ha = bft(ya), hb = bft(yb);
      hq[jj] = (__float_as_uint(ha) >> 16) | (__float_as_uint(hb) & 0xffff0000u);
      lq[jj] = bfpack(ya - ha, yb - hb);
    }
    const int pg = (g ^ hl) * 8;
    *(uint4*)(Wth + obase + pg) = make_uint4(hq[0], hq[1], hq[2], hq[3]);
    *(uint4*)(Wtl + obase + pg) = make_uint4(lq[0], lq[1], lq[2], lq[3]);
  }
}

// ---------------------------------------------------------------------------
// K4fused: Xm = LN2(relu(Xc @ Weff + mix_b)) where Xc (bf16 hi/lo) is
// RECOMPUTED per K-step (BK=32 == one channel c) by conv+LN1 MFMA directly
// into the As LDS buffer (D col=t2, row=f; ds_write in the proven swizzled
// As layout).  B (Weff) staging, main MFMA loop, LN2 epilogue identical to
// the passing round-5 k4.  One barrier per K-step; X loads + B glds16 issued
// before main MFMAs (latency hidden under compute).
// ---------------------------------------------------------------------------
__global__ __launch_bounds__(256, 2) void k4_fused(
    const float* __restrict__ X, const float* __restrict__ Wc,
    const float* __restrict__ bc, const float* __restrict__ g1,
    const float* __restrict__ be1,
    const u16* __restrict__ Bgh, const u16* __restrict__ Bgl,
    const float* __restrict__ mixb, const float* __restrict__ g2,
    const float* __restrict__ be2, float* __restrict__ Xm)
{
  // LDS: As[2][4096] (hi 2048 + lo 2048) @ 0; Bs[2][8192] (hi 4096+lo 4096) @ 8192
  __shared__ __align__(16) u16 lds[8192 + 16384];
  __shared__ float part[64 * 8];
  __shared__ float murs[128];

  const int tid = threadIdx.x;
  const int w = tid >> 6, lane = tid & 63;
  const int q = lane >> 4, cl = lane & 15;
  const int x = blockIdx.x;
  const int swz = (x & 7) * 64 + (x >> 3);      // bijective; same-b -> same XCD
  const int b = swz >> 4, mt = swz & 15;
  const int m0 = mt * 64;

  // ---- conv constants (same as k1) ----
  bf16x8 Wh[2][2], Wl[2][2];
#pragma unroll
  for (int s = 0; s < 2; ++s)
#pragma unroll
    for (int m2 = 0; m2 < 2; ++m2) {
      const int f = m2 * 16 + cl;
      float x8[8];
#pragma unroll
      for (int j = 0; j < 8; ++j) {
        float wv;
        if (s == 0) {
          wv = Wc[(q * 8 + j) * 32 + f];
        } else {
          wv = 0.f;
          if (q == 0) wv = Wc[(32 + j) * 32 + f];
          if (q == 1 && j == 0) wv = bc[f];
        }
        x8[j] = wv;
      }
      unsigned hu[4], lu[4];
#pragma unroll
      for (int p = 0; p < 4; ++p) {
        const float a0 = x8[2*p], a1 = x8[2*p+1];
        hu[p] = bfpack(a0, a1);
        lu[p] = bfpack(a0 - bft(a0), a1 - bft(a1));
      }
      uint4 hv = make_uint4(hu[0], hu[1], hu[2], hu[3]);
      uint4 lv = make_uint4(lu[0], lu[1], lu[2], lu[3]);
      Wh[s][m2] = *(bf16x8*)&hv;
      Wl[s][m2] = *(bf16x8*)&lv;
    }
  float g1r[2][4], be1r[2][4];
#pragma unroll
  for (int m2 = 0; m2 < 2; ++m2)
#pragma unroll
    for (int r = 0; r < 4; ++r) {
      const int f = m2 * 16 + 4 * q + r;
      g1r[m2][r] = g1[f];
      be1r[m2][r] = be1[f];
    }

  // ---- main GEMM constants ----
  f32x4 acc[4][2];
#pragma unroll
  for (int i = 0; i < 4; ++i)
#pragma unroll
    for (int j = 0; j < 2; ++j) acc[i][j] = (f32x4){0.f, 0.f, 0.f, 0.f};

  const int lrow = lane >> 2, lg = lane & 3;
  const size_t brow0 = (size_t)b * 262144 + (size_t)(w * 16 + lrow) * 32 + lg * 8;
  const int dA = w * 512;
  const int fa = cl * 32 + ((q ^ (cl & 3)) * 8);
  const float* Xb = X + (size_t)b * T_ * (C_ * FI_);
  const int t2 = m0 + w * 16 + cl;    // this lane's conv output row
  const int t2loc = w * 16 + cl;

#define STAGE_B(kt, buf) do {                                                \
    const int bb_ = 8192 + (buf) * 8192;                                     \
    glds16(Bgh + brow0 + (size_t)(kt) * 4096,        &lds[bb_ + dA]);        \
    glds16(Bgh + brow0 + (size_t)(kt) * 4096 + 2048, &lds[bb_ + 2048 + dA]); \
    glds16(Bgl + brow0 + (size_t)(kt) * 4096,        &lds[bb_ + 4096 + dA]); \
    glds16(Bgl + brow0 + (size_t)(kt) * 4096 + 2048, &lds[bb_ + 6144 + dA]); \
  } while (0)

  float4 xa0, xa1, xb0, xb1;
  bool ok0, ok1;
  auto loadX = [&](int c) {
    const float* base = Xb + (size_t)c * FI_;
    const int r0 = 2 * t2 + q - 1;
    ok0 = (r0 >= 0) && (r0 < T_);
    const float* p0 = base + (size_t)(ok0 ? r0 : 0) * (C_ * FI_);
    xa0 = *(const float4*)p0; xa1 = *(const float4*)(p0 + 4);
    const int r1 = 2 * t2 + 3;
    ok1 = (q == 0) && (r1 < T_);
    const float* p1 = base + (size_t)(ok1 ? r1 : 0) * (C_ * FI_);
    xb0 = *(const float4*)p1; xb1 = *(const float4*)(p1 + 4);
  };

  auto convStep = [&](int nb) {
    // pack conv B-frags from preloaded X regs
    bf16x8 Bh[2], Bl[2];
    {
      float x8[8] = {xa0.x, xa0.y, xa0.z, xa0.w, xa1.x, xa1.y, xa1.z, xa1.w};
#pragma unroll
      for (int j = 0; j < 8; ++j) x8[j] = ok0 ? x8[j] : 0.f;
      unsigned hu[4], lu[4];
#pragma unroll
      for (int p2 = 0; p2 < 4; ++p2) {
        const float a0 = x8[2*p2], a1 = x8[2*p2+1];
        const unsigned ph = cvtpk(a0, a1);
        hu[p2] = ph;
        const float f0 = __uint_as_float(ph << 16);
        const float f1 = __uint_as_float(ph & 0xffff0000u);
        lu[p2] = cvtpk(a0 - f0, a1 - f1);
      }
      uint4 hv = make_uint4(hu[0], hu[1], hu[2], hu[3]);
      uint4 lv = make_uint4(lu[0], lu[1], lu[2], lu[3]);
      Bh[0] = *(bf16x8*)&hv; Bl[0] = *(bf16x8*)&lv;
    }
    {
      float x8[8] = {xb0.x, xb0.y, xb0.z, xb0.w, xb1.x, xb1.y, xb1.z, xb1.w};
#pragma unroll
      for (int j = 0; j < 8; ++j) x8[j] = ok1 ? x8[j] : 0.f;
      unsigned hu[4], lu[4];
#pragma unroll
      for (int p2 = 0; p2 < 4; ++p2) {
        const float a0 = x8[2*p2], a1 = x8[2*p2+1];
        const unsigned ph = cvtpk(a0, a1);
        hu[p2] = ph;
        const float f0 = __uint_as_float(ph << 16);
        const float f1 = __uint_as_float(ph & 0xffff0000u);
        lu[p2] = cvtpk(a0 - f0, a1 - f1);
      }
      uint4 hv = make_uint4(hu[0], hu[1], hu[2], hu[3]);
      uint4 lv = make_uint4(lu[0], lu[1], lu[2], lu[3]);
      bf16x8 bh = *(bf16x8*)&hv, bl = *(bf16x8*)&lv;
      if (q == 1) bh[0] = (short)0x3F80;   // bias row k=40
      Bh[1] = bh; Bl[1] = bl;
    }
    // 12 conv MFMAs: D[f, t2]
    f32x4 ca[2] = {(f32x4){0.f,0.f,0.f,0.f}, (f32x4){0.f,0.f,0.f,0.f}};
#pragma unroll
    for (int m2 = 0; m2 < 2; ++m2)
#pragma unroll
      for (int s = 0; s < 2; ++s) {
        ca[m2] = __builtin_amdgcn_mfma_f32_16x16x32_bf16(Wh[s][m2], Bh[s], ca[m2], 0, 0, 0);
        ca[m2] = __builtin_amdgcn_mfma_f32_16x16x32_bf16(Wh[s][m2], Bl[s], ca[m2], 0, 0, 0);
        ca[m2] = __builtin_amdgcn_mfma_f32_16x16x32_bf16(Wl[s][m2], Bh[s], ca[m2], 0, 0, 0);
      }
    // relu + LN(32 over f) for this (t2, c)
    float v[2][4];
    float s1 = 0.f, s2 = 0.f;
#pragma unroll
    for (int m2 = 0; m2 < 2; ++m2)
#pragma unroll
      for (int r = 0; r < 4; ++r) {
        const float vv = fmaxf(ca[m2][r], 0.f);
        v[m2][r] = vv; s1 += vv; s2 = fmaf(vv, vv, s2);
      }
    s1 += __shfl_xor(s1, 16); s2 += __shfl_xor(s2, 16);
    s1 += __shfl_xor(s1, 32); s2 += __shfl_xor(s2, 32);
    const float mu = s1 * (1.f / 32.f);
    const float var = s2 * (1.f / 32.f) - mu * mu;
    const float rs = rsqrtf(var + 1e-6f);
    // pack hi/lo, ds_write into swizzled As layout
    const int AsB = nb * 4096;
#pragma unroll
    for (int m2 = 0; m2 < 2; ++m2) {
      float y[4];
#pragma unroll
      for (int r = 0; r < 4; ++r)
        y[r] = (v[m2][r] - mu) * rs * g1r[m2][r] + be1r[m2][r];
      const unsigned h0 = cvtpk(y[0], y[1]);
      const unsigned h1 = cvtpk(y[2], y[3]);
      const float f00 = __uint_as_float(h0 << 16);
      const float f01 = __uint_as_float(h0 & 0xffff0000u);
      const float f10 = __uint_as_float(h1 << 16);
      const float f11 = __uint_as_float(h1 & 0xffff0000u);
      const unsigned l0 = cvtpk(y[0] - f00, y[1] - f01);
      const unsigned l1 = cvtpk(y[2] - f10, y[3] - f11);
      const int pos = (((2 * m2 + (q >> 1)) ^ (cl & 3)) * 8) + (q & 1) * 4;
      *(uint2*)&lds[AsB + t2loc * 32 + pos] = make_uint2(h0, h1);
      *(uint2*)&lds[AsB + 2048 + t2loc * 32 + pos] = make_uint2(l0, l1);
    }
  };

  // ---- prologue: K-step 0 ----
  loadX(0);
  STAGE_B(0, 0);
  convStep(0);
  __syncthreads();

  int cur = 0;
  for (int kt = 0; kt < 64; ++kt) {
    if (kt < 63) { loadX(kt + 1); STAGE_B(kt + 1, cur ^ 1); }
    // main GEMM for K-step kt
    {
      const int ab = cur * 4096, bb = 8192 + cur * 8192;
      bf16x8 ah[4], al[4], bh[2], bl[2];
#pragma unroll
      for (int mf = 0; mf < 4; ++mf) {
        ah[mf] = *(const bf16x8*)&lds[ab + mf * 512 + fa];
        al[mf] = *(const bf16x8*)&lds[ab + 2048 + mf * 512 + fa];
      }
#pragma unroll
      for (int nf = 0; nf < 2; ++nf) {
        bh[nf] = *(const bf16x8*)&lds[bb + w * 1024 + nf * 512 + fa];
        bl[nf] = *(const bf16x8*)&lds[bb + 4096 + w * 1024 + nf * 512 + fa];
      }
#pragma unroll
      for (int mf = 0; mf < 4; ++mf)
#pragma unroll
        for (int nf = 0; nf < 2; ++nf) {
          acc[mf][nf] = __builtin_amdgcn_mfma_f32_16x16x32_bf16(ah[mf], bh[nf], acc[mf][nf], 0, 0, 0);
          acc[mf][nf] = __builtin_amdgcn_mfma_f32_16x16x32_bf16(ah[mf], bl[nf], acc[mf][nf], 0, 0, 0);
          acc[mf][nf] = __builtin_amdgcn_mfma_f32_16x16x32_bf16(al[mf], bh[nf], acc[mf][nf], 0, 0, 0);
        }
    }
    if (kt < 63) convStep(cur ^ 1);
    __syncthreads();
    cur ^= 1;
  }
#undef STAGE_B

  // ---- epilogue: +bias, relu, LN over 128 (identical to round-5 k4) ----
  const int c0 = w * 32 + (lane & 15);
  const float bias0 = mixb[c0], bias1 = mixb[c0 + 16];
#pragma unroll
  for (int mf = 0; mf < 4; ++mf)
#pragma unroll
    for (int r = 0; r < 4; ++r) {
      float v0 = fmaxf(acc[mf][0][r] + bias0, 0.f);
      float v1 = fmaxf(acc[mf][1][r] + bias1, 0.f);
      acc[mf][0][r] = v0; acc[mf][1][r] = v1;
      float s1 = v0 + v1, s2 = v0 * v0 + v1 * v1;
      s1 += __shfl_xor(s1, 1);  s2 += __shfl_xor(s2, 1);
      s1 += __shfl_xor(s1, 2);  s2 += __shfl_xor(s2, 2);
      s1 += __shfl_xor(s1, 4);  s2 += __shfl_xor(s2, 4);
      s1 += __shfl_xor(s1, 8);  s2 += __shfl_xor(s2, 8);
      if ((lane & 15) == 0) {
        const int row = mf * 16 + (lane >> 4) * 4 + r;
        part[row * 8 + w * 2] = s1;
        part[row * 8 + w * 2 + 1] = s2;
      }
    }
  __syncthreads();
  if (tid < 64) {
    const float s1 = part[tid*8] + part[tid*8+2] + part[tid*8+4] + part[tid*8+6];
    const float s2 = part[tid*8+1] + part[tid*8+3] + part[tid*8+5] + part[tid*8+7];
    const float mu = s1 * (1.f / 128.f);
    const float var = s2 * (1.f / 128.f) - mu * mu;
    murs[tid * 2] = mu;
    murs[tid * 2 + 1] = rsqrtf(var + 1e-6f);
  }
  __syncthreads();
  const float g20 = g2[c0], g21 = g2[c0 + 16];
  const float b20 = be2[c0], b21 = be2[c0 + 16];
#pragma unroll
  for (int mf = 0; mf < 4; ++mf)
#pragma unroll
    for (int r = 0; r < 4; ++r) {
      const int row = mf * 16 + (lane >> 4) * 4 + r;
      const float mu = murs[row * 2], rs = murs[row * 2 + 1];
      float* op = Xm + (size_t)(b * 1024 + m0 + row) * 128;
      op[c0]      = (acc[mf][0][r] - mu) * rs * g20 + b20;
      op[c0 + 16] = (acc[mf][1][r] - mu) * rs * g21 + b21;
    }
}

// ---------------------------------------------------------------------------
// K5: LIF scan, 4096 chains spread over 64 blocks
// ---------------------------------------------------------------------------
__global__ __launch_bounds__(64) void k5_lif(
    const float* __restrict__ Xm, const float* __restrict__ dl,
    float* __restrict__ fs)
{
  const int id = blockIdx.x * 64 + threadIdx.x;
  const int b = id >> 7, h = id & 127;
  const float decay = 1.f / (1.f + expf(-dl[h]));
  float mem = 0.f, cnt = 0.f;
  const float* p = Xm + (size_t)b * T2_ * H_ + h;
#pragma unroll 16
  for (int t = 0; t < T2_; ++t) {
    const float xv = p[(size_t)t * H_];
    mem = fmaf(mem, decay, xv);
    const float sp = ((mem - 0.5f) > 0.f) ? 1.f : 0.f;
    cnt += sp;
    mem -= 0.5f * sp;
  }
  fs[b * H_ + h] = cnt;
}

// ---------------------------------------------------------------------------
// K6: head
// ---------------------------------------------------------------------------
__global__ __launch_bounds__(256) void k6_head(
    const float* __restrict__ fs, const float* __restrict__ fcw,
    const float* __restrict__ fcb, const float* __restrict__ ow,
    const float* __restrict__ ob, float* __restrict__ out)
{
  __shared__ float f[32 * 128];
  __shared__ float fr[32 * 128];
  __shared__ float red[256];
  const int tid = threadIdx.x;
  float tot = 0.f;
  for (int idx = tid; idx < 4096; idx += 256) {
    const float v = fs[idx];
    f[idx] = v * (1.f / (float)T2_);
    tot += v;
  }
  red[tid] = tot;
  __syncthreads();
  for (int s = 128; s > 0; s >>= 1) {
    if (tid < s) red[tid] += red[tid + s];
    __syncthreads();
  }
  {
    const int bb = tid >> 3, og = tid & 7;
    float a[16];
#pragma unroll
    for (int j = 0; j < 16; ++j) a[j] = fcb[og * 16 + j];
    for (int hh = 0; hh < 128; ++hh) {
      const float fv = f[bb * 128 + hh];
#pragma unroll
      for (int j = 0; j < 16; ++j)
        a[j] = fmaf(fv, fcw[hh * 128 + og * 16 + j], a[j]);
    }
#pragma unroll
    for (int j = 0; j < 16; ++j) fr[bb * 128 + og * 16 + j] = fmaxf(a[j], 0.f);
  }
  __syncthreads();
  if (tid < 128) {
    const int bb = tid >> 2, cls = tid & 3;
    float a = ob[cls];
    for (int o = 0; o < 128; ++o) a = fmaf(fr[bb * 128 + o], ow[o * 4 + cls], a);
    out[bb * 4 + cls] = a;
  }
  if (tid == 0) out[128] = red[0] * (1.f / (4096.f * 1024.f));
}

// ---------------------------------------------------------------------------
extern "C" void kernel_launch(void* const* d_in, const int* in_sizes, int n_in,
                              void* d_out, int out_size, void* d_ws, size_t ws_size,
                              hipStream_t stream) {
  const float* X     = (const float*)d_in[0];
  const float* convw = (const float*)d_in[1];
  const float* convb = (const float*)d_in[2];
  const float* ln1s  = (const float*)d_in[3];
  const float* ln1b  = (const float*)d_in[4];
  const float* qw    = (const float*)d_in[5];
  const float* qb    = (const float*)d_in[6];
  const float* kw    = (const float*)d_in[7];
  const float* kb    = (const float*)d_in[8];
  const float* caw   = (const float*)d_in[9];
  const float* cab   = (const float*)d_in[10];
  const float* mixw  = (const float*)d_in[11];
  const float* mixb  = (const float*)d_in[12];
  const float* ln2s  = (const float*)d_in[13];
  const float* ln2b  = (const float*)d_in[14];
  const float* dl    = (const float*)d_in[15];
  const float* fcw   = (const float*)d_in[16];
  const float* fcb   = (const float*)d_in[17];
  const float* outw  = (const float*)d_in[18];
  const float* outb  = (const float*)d_in[19];

  float* ws  = (float*)d_ws;
  u16* Wth   = (u16*)(ws + OFF_WTH);
  u16* Wtl   = (u16*)(ws + OFF_WTL);
  float* xsp = ws + OFF_XSP;
  float* Aou = ws + OFF_A;
  float* Xm  = ws + OFF_XM;
  float* fs  = ws + OFF_A;   // reuse (A' dead after k3)

  dim3 g1(32, 32);
  k1_conv_ln<<<g1, 256, 0, stream>>>(X, convw, convb, ln1s, ln1b, xsp);
  k2_graph<<<32, 256, 0, stream>>>(xsp, qw, qb, kw, kb, caw, cab, Aou);
  k3_weff<<<1024, 256, 0, stream>>>(Aou, mixw, Wth, Wtl);
  k4_fused<<<512, 256, 0, stream>>>(X, convw, convb, ln1s, ln1b,
                                    Wth, Wtl, mixb, ln2s, ln2b, Xm);
  k5_lif<<<64, 64, 0, stream>>>(Xm, dl, fs);
  k6_head<<<1, 256, 0, stream>>>(fs, fcw, fcb, outw, outb, (float*)d_out);
}

// Round 7
// 307.421 us; speedup vs baseline: 2.4777x; 1.0246x over previous
//
#include <hip/hip_runtime.h>
#include <math.h>

#define B_    32
#define T_    2048
#define T2_   1024
#define C_    64
#define FI_   8
#define FO_   32
#define K_    2048   // C_*CONV_F
#define H_    128

typedef unsigned short u16;
typedef short bf16x8 __attribute__((ext_vector_type(8)));
typedef float f32x4 __attribute__((ext_vector_type(4)));

// workspace offsets (in FLOAT units)
#define OFF_WTH  ((size_t)67108864)   // bf16 hi Weff_T
#define OFF_WTL  ((size_t)71303168)
#define OFF_XSP  ((size_t)75497472)   // 32*32*2048 f32
#define OFF_A    ((size_t)77594624)   // 32*64*64 f32 (A'); reused later for fs
#define OFF_XM   ((size_t)77725696)   // 32*1024*128 f32

// ---- bf16 helpers --------------------------------------------------------
__device__ __forceinline__ float bft(float x) {  // value of bf16-rounded x
  unsigned u = __float_as_uint(x);
  u = (u + 0x7fffu + ((u >> 16) & 1u)) & 0xffff0000u;
  return __uint_as_float(u);
}
__device__ __forceinline__ unsigned bfpack(float a, float b) { // manual RTNE
  unsigned ua = __float_as_uint(a); ua = (ua + 0x7fffu + ((ua >> 16) & 1u)) >> 16;
  unsigned ub = __float_as_uint(b); ub = (ub + 0x7fffu + ((ub >> 16) & 1u)) & 0xffff0000u;
  return ua | ub;
}
// HW packed convert (RTNE): lo16 = bf16(a), hi16 = bf16(b) - 1 instruction
__device__ __forceinline__ unsigned cvtpk(float a, float b) {
  unsigned r;
  asm("v_cvt_pk_bf16_f32 %0, %1, %2" : "=v"(r) : "v"(a), "v"(b));
  return r;
}
// hi-only pack of 8 floats
__device__ __forceinline__ bf16x8 packhi(const float4& x0, const float4& x1) {
  uint4 hv = make_uint4(cvtpk(x0.x, x0.y), cvtpk(x0.z, x0.w),
                        cvtpk(x1.x, x1.y), cvtpk(x1.z, x1.w));
  return *(bf16x8*)&hv;
}
// hi+lo split pack of 8 floats
__device__ __forceinline__ void pack8(const float4& x0, const float4& x1,
                                      bf16x8& h, bf16x8& l) {
  float v[8] = {x0.x, x0.y, x0.z, x0.w, x1.x, x1.y, x1.z, x1.w};
  unsigned hu[4], lu[4];
#pragma unroll
  for (int p = 0; p < 4; ++p) {
    const float a = v[2*p], b2 = v[2*p+1];
    const unsigned ph = cvtpk(a, b2);
    hu[p] = ph;
    const float fa_ = __uint_as_float(ph << 16);
    const float fb_ = __uint_as_float(ph & 0xffff0000u);
    lu[p] = cvtpk(a - fa_, b2 - fb_);
  }
  uint4 hv = make_uint4(hu[0], hu[1], hu[2], hu[3]);
  uint4 lv = make_uint4(lu[0], lu[1], lu[2], lu[3]);
  h = *(bf16x8*)&hv; l = *(bf16x8*)&lv;
}

// async global->LDS, 16B per lane; LDS dest must be wave-uniform base
__device__ __forceinline__ void glds16(const u16* g, u16* l) {
  auto gp = reinterpret_cast<const __attribute__((address_space(1))) unsigned int*>(
      reinterpret_cast<uintptr_t>(g));
  auto lp = reinterpret_cast<__attribute__((address_space(3))) unsigned int*>(
      reinterpret_cast<uintptr_t>(l));
  __builtin_amdgcn_global_load_lds(gp, lp, 16, 0, 0);
}

// ---------------------------------------------------------------------------
// K1lite: conv(5x1,s2,SAME)+bias+relu+LN(32) -> ONLY xsp mean partials.
// Mean-path precision: X as bf16-hi only (random rounding averages out over
// t2); weights keep hi/lo (systematic). 8 MFMAs per (t2,nt).  unroll 2 for
// cross-iteration ILP; s=1 loads exec-predicated (only q==0 lanes fetch).
// ---------------------------------------------------------------------------
__global__ __launch_bounds__(256, 3) void k1_conv_ln(
    const float* __restrict__ X, const float* __restrict__ Wc,
    const float* __restrict__ bc, const float* __restrict__ g1,
    const float* __restrict__ be1, float* __restrict__ xsp)
{
  __shared__ float xred[4][1056];
  const int tid = threadIdx.x;
  const int w = tid >> 6, lane = tid & 63;
  const int q = lane >> 4, cl = lane & 15;
  const int chalf = w & 1, rng = w >> 1;
  const int b = blockIdx.y, tile = blockIdx.x;
  const int cbase = chalf * 32;

  // constant A-frags (weights; bias row at k=40), hi/lo split
  bf16x8 Wh[2][2], Wl[2][2];
#pragma unroll
  for (int s = 0; s < 2; ++s)
#pragma unroll
    for (int mt = 0; mt < 2; ++mt) {
      const int f = mt * 16 + cl;
      float x8[8];
#pragma unroll
      for (int j = 0; j < 8; ++j) {
        float wv;
        if (s == 0) {
          wv = Wc[(q * 8 + j) * 32 + f];
        } else {
          wv = 0.f;
          if (q == 0) wv = Wc[(32 + j) * 32 + f];
          if (q == 1 && j == 0) wv = bc[f];
        }
        x8[j] = wv;
      }
      unsigned hu[4], lu[4];
#pragma unroll
      for (int p = 0; p < 4; ++p) {
        const float a0 = x8[2*p], a1 = x8[2*p+1];
        hu[p] = bfpack(a0, a1);
        lu[p] = bfpack(a0 - bft(a0), a1 - bft(a1));
      }
      uint4 hv = make_uint4(hu[0], hu[1], hu[2], hu[3]);
      uint4 lv = make_uint4(lu[0], lu[1], lu[2], lu[3]);
      Wh[s][mt] = *(bf16x8*)&hv;
      Wl[s][mt] = *(bf16x8*)&lv;
    }

  float g1r[2][4], be1r[2][4];
#pragma unroll
  for (int mt = 0; mt < 2; ++mt)
#pragma unroll
    for (int r = 0; r < 4; ++r) {
      const int f = mt * 16 + 4 * q + r;
      g1r[mt][r] = g1[f];
      be1r[mt][r] = be1[f];
    }

  float sacc[2][2][4];
#pragma unroll
  for (int mt = 0; mt < 2; ++mt)
#pragma unroll
    for (int nt = 0; nt < 2; ++nt)
#pragma unroll
      for (int r = 0; r < 4; ++r) sacc[mt][nt][r] = 0.f;

  const float* Xb = X + (size_t)b * T_ * C_ * FI_;
  const float4 z4f = make_float4(0.f, 0.f, 0.f, 0.f);

#pragma unroll 2
  for (int it = 0; it < 16; ++it) {
    const int t2 = tile * 32 + rng * 16 + it;
    f32x4 acc[2][2];
#pragma unroll
    for (int mt = 0; mt < 2; ++mt)
#pragma unroll
      for (int nt = 0; nt < 2; ++nt) acc[mt][nt] = (f32x4){0.f,0.f,0.f,0.f};

#pragma unroll
    for (int nt = 0; nt < 2; ++nt) {
      const int c = cbase + nt * 16 + cl;
      const float* Xbc = Xb + (size_t)c * FI_;
      bf16x8 Bh0, Bh1;
      {
        const int row = 2 * t2 + q - 1;
        const bool ok = (row >= 0) && (row < T_);
        float4 xa = z4f, xb2 = z4f;
        if (ok) {
          const float* p = Xbc + (size_t)row * (C_ * FI_);
          xa = *(const float4*)p; xb2 = *(const float4*)(p + 4);
        }
        Bh0 = packhi(xa, xb2);
      }
      {
        const int row = 2 * t2 + 3;
        const bool ok = (q == 0) && (row < T_);
        float4 xa = z4f, xb2 = z4f;
        if (ok) {
          const float* p = Xbc + (size_t)row * (C_ * FI_);
          xa = *(const float4*)p; xb2 = *(const float4*)(p + 4);
        }
        Bh1 = packhi(xa, xb2);
        if (q == 1) Bh1[0] = (short)0x3F80;  // bias row k=40
      }
#pragma unroll
      for (int mt = 0; mt < 2; ++mt) {
        acc[mt][nt] = __builtin_amdgcn_mfma_f32_16x16x32_bf16(Wh[0][mt], Bh0, acc[mt][nt], 0, 0, 0);
        acc[mt][nt] = __builtin_amdgcn_mfma_f32_16x16x32_bf16(Wl[0][mt], Bh0, acc[mt][nt], 0, 0, 0);
        acc[mt][nt] = __builtin_amdgcn_mfma_f32_16x16x32_bf16(Wh[1][mt], Bh1, acc[mt][nt], 0, 0, 0);
        acc[mt][nt] = __builtin_amdgcn_mfma_f32_16x16x32_bf16(Wl[1][mt], Bh1, acc[mt][nt], 0, 0, 0);
      }
    }

    // relu + LN(32) -> accumulate mean only
#pragma unroll
    for (int nt = 0; nt < 2; ++nt) {
      float v[2][4];
      float s1 = 0.f, s2 = 0.f;
#pragma unroll
      for (int mt = 0; mt < 2; ++mt)
#pragma unroll
        for (int r = 0; r < 4; ++r) {
          const float vv = fmaxf(acc[mt][nt][r], 0.f);
          v[mt][r] = vv; s1 += vv; s2 = fmaf(vv, vv, s2);
        }
      s1 += __shfl_xor(s1, 16); s2 += __shfl_xor(s2, 16);
      s1 += __shfl_xor(s1, 32); s2 += __shfl_xor(s2, 32);
      const float mu = s1 * (1.f / 32.f);
      const float var = s2 * (1.f / 32.f) - mu * mu;
      const float rs = rsqrtf(var + 1e-6f);
#pragma unroll
      for (int mt = 0; mt < 2; ++mt)
#pragma unroll
        for (int r = 0; r < 4; ++r)
          sacc[mt][nt][r] += (v[mt][r] - mu) * rs * g1r[mt][r] + be1r[mt][r];
    }
  }

  // cross-wave (rng) reduce via LDS, write xsp partials
#pragma unroll
  for (int mt = 0; mt < 2; ++mt)
#pragma unroll
    for (int nt = 0; nt < 2; ++nt)
#pragma unroll
      for (int r = 0; r < 4; ++r)
        xred[w][(nt * 16 + cl) * 33 + mt * 16 + 4 * q + r] = sacc[mt][nt][r];
  __syncthreads();
  if (w < 2) {
#pragma unroll
    for (int mt = 0; mt < 2; ++mt)
#pragma unroll
      for (int nt = 0; nt < 2; ++nt)
#pragma unroll
        for (int r = 0; r < 4; ++r) {
          const int idx = (nt * 16 + cl) * 33 + mt * 16 + 4 * q + r;
          const float vv = xred[w][idx] + xred[w + 2][idx];
          xsp[((size_t)b * 32 + tile) * 2048 +
              (size_t)(w * 32 + nt * 16 + cl) * 32 + mt * 16 + 4 * q + r] = vv;
        }
  }
}

// ---------------------------------------------------------------------------
// K2: x_spat reduce, q/k, adj=softmax, ca=sigmoid; A'[c][d] = ca[c]adj[c,d]+I
// ---------------------------------------------------------------------------
__global__ __launch_bounds__(256) void k2_graph(
    const float* __restrict__ xsp, const float* __restrict__ qw,
    const float* __restrict__ qb, const float* __restrict__ kw,
    const float* __restrict__ kb, const float* __restrict__ caw,
    const float* __restrict__ cab, float* __restrict__ Aout)
{
  __shared__ float xs[64 * 32];
  __shared__ float qs[64][32];
  __shared__ float ks[64][32];
  __shared__ float sc[64][64];
  __shared__ float cain[64];
  __shared__ float cav[64];
  const int tid = threadIdx.x;
  const int b = blockIdx.x;

  for (int idx = tid; idx < 2048; idx += 256) {
    float s = 0.f;
    for (int p = 0; p < 32; ++p) s += xsp[((size_t)b * 32 + p) * 2048 + idx];
    xs[idx] = s * (1.f / (float)T2_);
  }
  __syncthreads();

  if (tid < 64) {
    float s = 0.f;
#pragma unroll
    for (int f = 0; f < 32; ++f) s += xs[tid * 32 + f];
    cain[tid] = s * (1.f / 32.f);
  }
  {
    const int cc = tid >> 2, part = tid & 3;
    float aq[8], ak[8];
#pragma unroll
    for (int j = 0; j < 8; ++j) { aq[j] = qb[part*8+j]; ak[j] = kb[part*8+j]; }
    for (int f = 0; f < 32; ++f) {
      const float xv = xs[cc * 32 + f];
#pragma unroll
      for (int j = 0; j < 8; ++j) {
        aq[j] = fmaf(xv, qw[f * 32 + part*8+j], aq[j]);
        ak[j] = fmaf(xv, kw[f * 32 + part*8+j], ak[j]);
      }
    }
#pragma unroll
    for (int j = 0; j < 8; ++j) { qs[cc][part*8+j] = aq[j]; ks[cc][part*8+j] = ak[j]; }
  }
  __syncthreads();
  {
    const int cc = tid >> 2, part = tid & 3;
    for (int dd = part * 16; dd < part * 16 + 16; ++dd) {
      float s = 0.f;
#pragma unroll
      for (int e = 0; e < 32; ++e) s = fmaf(qs[cc][e], ks[dd][e], s);
      sc[cc][dd] = s * 0.1767766953f;
    }
  }
  __syncthreads();
  if (tid < 64) {
    const int cc = tid;
    float m = -1e30f;
    for (int d = 0; d < 64; ++d) m = fmaxf(m, sc[cc][d]);
    float sum = 0.f;
    for (int d = 0; d < 64; ++d) { float e = expf(sc[cc][d] - m); sc[cc][d] = e; sum += e; }
    const float inv = 1.f / sum;
    for (int d = 0; d < 64; ++d) sc[cc][d] *= inv;
    float a = cab[cc];
    for (int d = 0; d < 64; ++d) a = fmaf(cain[d], caw[d * 64 + cc], a);
    cav[cc] = 1.f / (1.f + expf(-a));
  }
  __syncthreads();
  for (int idx = tid; idx < 4096; idx += 256) {
    const int cc = idx >> 6, dd = idx & 63;
    Aout[(size_t)b * 4096 + idx] = cav[cc] * sc[cc][dd] + (cc == dd ? 1.f : 0.f);
  }
}

// ---------------------------------------------------------------------------
// K3: Weff_T[b][c][h][f] = sum_cc A'[cc][c... ] mixw..., bf16 hi/lo.
// Chunk pre-swizzle strengthened: phys g = g ^ (h&3) ^ ((h>>2)&3) so k4's
// Bs ds_read_b128 slots spread to 2-way (was 4 lanes/slot).
// ---------------------------------------------------------------------------
__global__ __launch_bounds__(256) void k3_weff(
    const float* __restrict__ Aout, const float* __restrict__ mixw,
    u16* __restrict__ Wth, u16* __restrict__ Wtl)
{
  __shared__ float Ap[4096];
  __shared__ float Ms[2048];
  const int tid = threadIdx.x;
  const int b = blockIdx.x >> 5, ht = blockIdx.x & 31;
  const int d = tid & 63, hl = tid >> 6;
  const int h0 = ht * 4;
  const float* Ab = Aout + (size_t)b * 4096;
#pragma unroll
  for (int l = 0; l < 16; ++l) Ap[tid + 256 * l] = Ab[tid + 256 * l];

  float acc[32];
#pragma unroll
  for (int j = 0; j < 32; ++j) acc[j] = 0.f;

  for (int c0 = 0; c0 < 64; c0 += 16) {
    __syncthreads();
    {
      const int i0 = tid * 8;
#pragma unroll
      for (int qd = 0; qd < 2; ++qd) {
        const int i = i0 + qd * 4;
        const int cc = i >> 7, f = (i >> 2) & 31;
        const float4 v = *(const float4*)&mixw[((size_t)((c0+cc)*32 + f))*128 + h0];
        float* mp = &Ms[cc * 128 + f];
        mp[0] = v.x; mp[32] = v.y; mp[64] = v.z; mp[96] = v.w;
      }
    }
    __syncthreads();
#pragma unroll 4
    for (int cc = 0; cc < 16; ++cc) {
      const float a = Ap[(c0 + cc) * 64 + d];
      const float* mrow = &Ms[cc * 128 + hl * 32];
#pragma unroll
      for (int fq = 0; fq < 8; ++fq) {
        const f32x4 m = *(const f32x4*)&mrow[fq * 4];
        acc[fq*4+0] = fmaf(a, m[0], acc[fq*4+0]);
        acc[fq*4+1] = fmaf(a, m[1], acc[fq*4+1]);
        acc[fq*4+2] = fmaf(a, m[2], acc[fq*4+2]);
        acc[fq*4+3] = fmaf(a, m[3], acc[fq*4+3]);
      }
    }
  }

  const int h = h0 + hl;
  const size_t obase = ((size_t)(b * 64 + d) * 128 + h) * 32;
#pragma unroll
  for (int g = 0; g < 4; ++g) {
    unsigned hq[4], lq[4];
#pragma unroll
    for (int jj = 0; jj < 4; ++jj) {
      const float ya = acc[8*g + 2*jj], yb = acc[8*g + 2*jj + 1];
      const float ha = bft(ya), hb = bft(yb);
      hq[jj] = (__float_as_uint(ha) >> 16) | (__float_as_uint(hb) & 0xffff0000u);
      lq[jj] = bfpack(ya - ha, yb - hb);
    }
    const int pg = (g ^ hl ^ (ht & 3)) * 8;   // h&3 == hl, (h>>2)&3 == ht&3
    *(uint4*)(Wth + obase + pg) = make_uint4(hq[0], hq[1], hq[2], hq[3]);
    *(uint4*)(Wtl + obase + pg) = make_uint4(lq[0], lq[1], lq[2], lq[3]);
  }
}

// ---------------------------------------------------------------------------
// K4fused: Xm = LN2(relu(Xc @ Weff + mix_b)); Xc recomputed per K-step.
// Changes vs round 6: (1) As row stride 32->40 u16 (kills 4-way ds_write
// bank conflict; 80B rows stay 16B-aligned); (2) Bs chunk swizzle includes
// (h>>2)&3 (matches k3) -> 2-way reads; (3) X double-buffered in registers
// (issue ch kt+2 at step kt, consume kt+1) via manually 2-unrolled loop with
// named register sets (no runtime-indexed arrays); (4) s=1 X loads predicated.
// ---------------------------------------------------------------------------
__global__ __launch_bounds__(256, 2) void k4_fused(
    const float* __restrict__ X, const float* __restrict__ Wc,
    const float* __restrict__ bc, const float* __restrict__ g1,
    const float* __restrict__ be1,
    const u16* __restrict__ Bgh, const u16* __restrict__ Bgl,
    const float* __restrict__ mixb, const float* __restrict__ g2,
    const float* __restrict__ be2, float* __restrict__ Xm)
{
  // As: 2 bufs x (hi 2560 + lo 2560) u16 @ 0 (row stride 40)
  // Bs: 2 bufs x (hi 4096 + lo 4096) u16 @ 10240 (linear, glds16-staged)
  __shared__ __align__(16) u16 lds[26624];
  __shared__ float part[64 * 8];
  __shared__ float murs[128];

  const int tid = threadIdx.x;
  const int w = tid >> 6, lane = tid & 63;
  const int q = lane >> 4, cl = lane & 15;
  const int x = blockIdx.x;
  const int swz = (x & 7) * 64 + (x >> 3);      // bijective; same-b -> same XCD
  const int b = swz >> 4, mt = swz & 15;
  const int m0 = mt * 64;

  // ---- conv constants ----
  bf16x8 Wh[2][2], Wl[2][2];
#pragma unroll
  for (int s = 0; s < 2; ++s)
#pragma unroll
    for (int m2 = 0; m2 < 2; ++m2) {
      const int f = m2 * 16 + cl;
      float x8[8];
#pragma unroll
      for (int j = 0; j < 8; ++j) {
        float wv;
        if (s == 0) {
          wv = Wc[(q * 8 + j) * 32 + f];
        } else {
          wv = 0.f;
          if (q == 0) wv = Wc[(32 + j) * 32 + f];
          if (q == 1 && j == 0) wv = bc[f];
        }
        x8[j] = wv;
      }
      unsigned hu[4], lu[4];
#pragma unroll
      for (int p = 0; p < 4; ++p) {
        const float a0 = x8[2*p], a1 = x8[2*p+1];
        hu[p] = bfpack(a0, a1);
        lu[p] = bfpack(a0 - bft(a0), a1 - bft(a1));
      }
      uint4 hv = make_uint4(hu[0], hu[1], hu[2], hu[3]);
      uint4 lv = make_uint4(lu[0], lu[1], lu[2], lu[3]);
      Wh[s][m2] = *(bf16x8*)&hv;
      Wl[s][m2] = *(bf16x8*)&lv;
    }
  float g1r[2][4], be1r[2][4];
#pragma unroll
  for (int m2 = 0; m2 < 2; ++m2)
#pragma unroll
    for (int r = 0; r < 4; ++r) {
      const int f = m2 * 16 + 4 * q + r;
      g1r[m2][r] = g1[f];
      be1r[m2][r] = be1[f];
    }

  f32x4 acc[4][2];
#pragma unroll
  for (int i = 0; i < 4; ++i)
#pragma unroll
    for (int j = 0; j < 2; ++j) acc[i][j] = (f32x4){0.f, 0.f, 0.f, 0.f};

  const int lrow = lane >> 2, lg = lane & 3;
  const size_t brow0 = (size_t)b * 262144 + (size_t)(w * 16 + lrow) * 32 + lg * 8;
  const int dA = w * 512;
  const int faA = cl * 40 + ((q ^ (cl & 3)) * 8);
  const int faB = cl * 32 + ((q ^ (cl & 3) ^ (cl >> 2)) * 8);
  const float* Xb = X + (size_t)b * T_ * (C_ * FI_);
  const int t2 = m0 + w * 16 + cl;
  const int t2loc = w * 16 + cl;

  // loop-invariant conv-row addressing
  const int r0 = 2 * t2 + q - 1, r1 = 2 * t2 + 3;
  const bool ok0 = (r0 >= 0) && (r0 < T_);
  const bool ok1 = (q == 0) && (r1 < T_);
  const float* rp0 = Xb + (size_t)(ok0 ? r0 : 0) * (C_ * FI_);
  const float* rp1 = Xb + (size_t)(ok1 ? r1 : 0) * (C_ * FI_);
  const float4 z4f = make_float4(0.f, 0.f, 0.f, 0.f);

  float4 A0a, A1a, B0a, B1a;   // X set A (even channels)
  float4 A0b, A1b, B0b, B1b;   // X set B (odd channels)

  auto LOADX = [&](float4& X0, float4& X1, float4& Y0, float4& Y1, int c) {
    X0 = z4f; X1 = z4f; Y0 = z4f; Y1 = z4f;
    if (ok0) { const float* p = rp0 + c * FI_; X0 = *(const float4*)p; X1 = *(const float4*)(p + 4); }
    if (ok1) { const float* p = rp1 + c * FI_; Y0 = *(const float4*)p; Y1 = *(const float4*)(p + 4); }
  };

  auto CONV = [&](const float4& X0, const float4& X1,
                  const float4& Y0, const float4& Y1, int nb) {
    bf16x8 Bh0, Bl0, Bh1, Bl1;
    pack8(X0, X1, Bh0, Bl0);
    pack8(Y0, Y1, Bh1, Bl1);
    if (q == 1) Bh1[0] = (short)0x3F80;   // bias row k=40 (lo stays 0)
    f32x4 ca0 = (f32x4){0.f,0.f,0.f,0.f}, ca1 = ca0;
    ca0 = __builtin_amdgcn_mfma_f32_16x16x32_bf16(Wh[0][0], Bh0, ca0, 0, 0, 0);
    ca1 = __builtin_amdgcn_mfma_f32_16x16x32_bf16(Wh[0][1], Bh0, ca1, 0, 0, 0);
    ca0 = __builtin_amdgcn_mfma_f32_16x16x32_bf16(Wh[0][0], Bl0, ca0, 0, 0, 0);
    ca1 = __builtin_amdgcn_mfma_f32_16x16x32_bf16(Wh[0][1], Bl0, ca1, 0, 0, 0);
    ca0 = __builtin_amdgcn_mfma_f32_16x16x32_bf16(Wl[0][0], Bh0, ca0, 0, 0, 0);
    ca1 = __builtin_amdgcn_mfma_f32_16x16x32_bf16(Wl[0][1], Bh0, ca1, 0, 0, 0);
    ca0 = __builtin_amdgcn_mfma_f32_16x16x32_bf16(Wh[1][0], Bh1, ca0, 0, 0, 0);
    ca1 = __builtin_amdgcn_mfma_f32_16x16x32_bf16(Wh[1][1], Bh1, ca1, 0, 0, 0);
    ca0 = __builtin_amdgcn_mfma_f32_16x16x32_bf16(Wh[1][0], Bl1, ca0, 0, 0, 0);
    ca1 = __builtin_amdgcn_mfma_f32_16x16x32_bf16(Wh[1][1], Bl1, ca1, 0, 0, 0);
    ca0 = __builtin_amdgcn_mfma_f32_16x16x32_bf16(Wl[1][0], Bh1, ca0, 0, 0, 0);
    ca1 = __builtin_amdgcn_mfma_f32_16x16x32_bf16(Wl[1][1], Bh1, ca1, 0, 0, 0);
    // relu + LN(32 over f)
    float v[2][4];
    float s1 = 0.f, s2 = 0.f;
#pragma unroll
    for (int r = 0; r < 4; ++r) {
      float vv = fmaxf(ca0[r], 0.f); v[0][r] = vv; s1 += vv; s2 = fmaf(vv, vv, s2);
      vv = fmaxf(ca1[r], 0.f);       v[1][r] = vv; s1 += vv; s2 = fmaf(vv, vv, s2);
    }
    s1 += __shfl_xor(s1, 16); s2 += __shfl_xor(s2, 16);
    s1 += __shfl_xor(s1, 32); s2 += __shfl_xor(s2, 32);
    const float mu = s1 * (1.f / 32.f);
    const float var = s2 * (1.f / 32.f) - mu * mu;
    const float rs = rsqrtf(var + 1e-6f);
    const int ab = nb * 5120;
#pragma unroll
    for (int m2 = 0; m2 < 2; ++m2) {
      float y[4];
#pragma unroll
      for (int r = 0; r < 4; ++r)
        y[r] = (v[m2][r] - mu) * rs * g1r[m2][r] + be1r[m2][r];
      const unsigned h0 = cvtpk(y[0], y[1]);
      const unsigned h1 = cvtpk(y[2], y[3]);
      const float f00 = __uint_as_float(h0 << 16);
      const float f01 = __uint_as_float(h0 & 0xffff0000u);
      const float f10 = __uint_as_float(h1 << 16);
      const float f11 = __uint_as_float(h1 & 0xffff0000u);
      const unsigned l0 = cvtpk(y[0] - f00, y[1] - f01);
      const unsigned l1 = cvtpk(y[2] - f10, y[3] - f11);
      const int phys = (2 * m2 + (q >> 1)) ^ (cl & 3);
      const int off = ab + t2loc * 40 + phys * 8 + (q & 1) * 4;
      *(uint2*)&lds[off] = make_uint2(h0, h1);
      *(uint2*)&lds[off + 2560] = make_uint2(l0, l1);
    }
  };

#define STAGE_B(kt, nb) do {                                                 \
    const int bb_ = 10240 + (nb) * 8192;                                     \
    glds16(Bgh + brow0 + (size_t)(kt) * 4096,        &lds[bb_ + dA]);        \
    glds16(Bgh + brow0 + (size_t)(kt) * 4096 + 2048, &lds[bb_ + 2048 + dA]); \
    glds16(Bgl + brow0 + (size_t)(kt) * 4096,        &lds[bb_ + 4096 + dA]); \
    glds16(Bgl + brow0 + (size_t)(kt) * 4096 + 2048, &lds[bb_ + 6144 + dA]); \
  } while (0)

  auto GEMM = [&](int nb) {
    const int ab = nb * 5120, bb = 10240 + nb * 8192;
    bf16x8 ah[4], al[4], bh[2], bl[2];
#pragma unroll
    for (int mf = 0; mf < 4; ++mf) {
      ah[mf] = *(const bf16x8*)&lds[ab + mf * 640 + faA];
      al[mf] = *(const bf16x8*)&lds[ab + 2560 + mf * 640 + faA];
    }
#pragma unroll
    for (int nf = 0; nf < 2; ++nf) {
      bh[nf] = *(const bf16x8*)&lds[bb + w * 1024 + nf * 512 + faB];
      bl[nf] = *(const bf16x8*)&lds[bb + 4096 + w * 1024 + nf * 512 + faB];
    }
#pragma unroll
    for (int mf = 0; mf < 4; ++mf)
#pragma unroll
      for (int nf = 0; nf < 2; ++nf) {
        acc[mf][nf] = __builtin_amdgcn_mfma_f32_16x16x32_bf16(ah[mf], bh[nf], acc[mf][nf], 0, 0, 0);
        acc[mf][nf] = __builtin_amdgcn_mfma_f32_16x16x32_bf16(ah[mf], bl[nf], acc[mf][nf], 0, 0, 0);
        acc[mf][nf] = __builtin_amdgcn_mfma_f32_16x16x32_bf16(al[mf], bh[nf], acc[mf][nf], 0, 0, 0);
      }
  };

  // ---- prologue ----
  LOADX(A0a, A1a, B0a, B1a, 0);
  STAGE_B(0, 0);
  LOADX(A0b, A1b, B0b, B1b, 1);
  CONV(A0a, A1a, B0a, B1a, 0);
  __syncthreads();

  for (int kt = 0; kt < 64; kt += 2) {
    // even step kt: GEMM buf0 (ch kt); conv ch kt+1 -> buf1; prefetch A <- kt+2
    if (kt + 2 < 64) LOADX(A0a, A1a, B0a, B1a, kt + 2);
    STAGE_B(kt + 1, 1);
    GEMM(0);
    CONV(A0b, A1b, B0b, B1b, 1);
    __syncthreads();
    // odd step kt+1: GEMM buf1 (ch kt+1); conv ch kt+2 -> buf0; prefetch B <- kt+3
    if (kt + 3 < 64) LOADX(A0b, A1b, B0b, B1b, kt + 3);
    if (kt + 2 < 64) STAGE_B(kt + 2, 0);
    GEMM(1);
    if (kt + 2 < 64) CONV(A0a, A1a, B0a, B1a, 0);
    __syncthreads();
  }
#undef STAGE_B

  // ---- epilogue: +bias, relu, LN over 128 ----
  const int c0 = w * 32 + (lane & 15);
  const float bias0 = mixb[c0], bias1 = mixb[c0 + 16];
#pragma unroll
  for (int mf = 0; mf < 4; ++mf)
#pragma unroll
    for (int r = 0; r < 4; ++r) {
      float v0 = fmaxf(acc[mf][0][r] + bias0, 0.f);
      float v1 = fmaxf(acc[mf][1][r] + bias1, 0.f);
      acc[mf][0][r] = v0; acc[mf][1][r] = v1;
      float s1 = v0 + v1, s2 = v0 * v0 + v1 * v1;
      s1 += __shfl_xor(s1, 1);  s2 += __shfl_xor(s2, 1);
      s1 += __shfl_xor(s1, 2);  s2 += __shfl_xor(s2, 2);
      s1 += __shfl_xor(s1, 4);  s2 += __shfl_xor(s2, 4);
      s1 += __shfl_xor(s1, 8);  s2 += __shfl_xor(s2, 8);
      if ((lane & 15) == 0) {
        const int row = mf * 16 + (lane >> 4) * 4 + r;
        part[row * 8 + w * 2] = s1;
        part[row * 8 + w * 2 + 1] = s2;
      }
    }
  __syncthreads();
  if (tid < 64) {
    const float s1 = part[tid*8] + part[tid*8+2] + part[tid*8+4] + part[tid*8+6];
    const float s2 = part[tid*8+1] + part[tid*8+3] + part[tid*8+5] + part[tid*8+7];
    const float mu = s1 * (1.f / 128.f);
    const float var = s2 * (1.f / 128.f) - mu * mu;
    murs[tid * 2] = mu;
    murs[tid * 2 + 1] = rsqrtf(var + 1e-6f);
  }
  __syncthreads();
  const float g20 = g2[c0], g21 = g2[c0 + 16];
  const float b20 = be2[c0], b21 = be2[c0 + 16];
#pragma unroll
  for (int mf = 0; mf < 4; ++mf)
#pragma unroll
    for (int r = 0; r < 4; ++r) {
      const int row = mf * 16 + (lane >> 4) * 4 + r;
      const float mu = murs[row * 2], rs = murs[row * 2 + 1];
      float* op = Xm + (size_t)(b * 1024 + m0 + row) * 128;
      op[c0]      = (acc[mf][0][r] - mu) * rs * g20 + b20;
      op[c0 + 16] = (acc[mf][1][r] - mu) * rs * g21 + b21;
    }
}

// ---------------------------------------------------------------------------
// K5: LIF scan, 4096 chains spread over 64 blocks
// ---------------------------------------------------------------------------
__global__ __launch_bounds__(64) void k5_lif(
    const float* __restrict__ Xm, const float* __restrict__ dl,
    float* __restrict__ fs)
{
  const int id = blockIdx.x * 64 + threadIdx.x;
  const int b = id >> 7, h = id & 127;
  const float decay = 1.f / (1.f + expf(-dl[h]));
  float mem = 0.f, cnt = 0.f;
  const float* p = Xm + (size_t)b * T2_ * H_ + h;
#pragma unroll 16
  for (int t = 0; t < T2_; ++t) {
    const float xv = p[(size_t)t * H_];
    mem = fmaf(mem, decay, xv);
    const float sp = ((mem - 0.5f) > 0.f) ? 1.f : 0.f;
    cnt += sp;
    mem -= 0.5f * sp;
  }
  fs[b * H_ + h] = cnt;
}

// ---------------------------------------------------------------------------
// K6: head
// ---------------------------------------------------------------------------
__global__ __launch_bounds__(256) void k6_head(
    const float* __restrict__ fs, const float* __restrict__ fcw,
    const float* __restrict__ fcb, const float* __restrict__ ow,
    const float* __restrict__ ob, float* __restrict__ out)
{
  __shared__ float f[32 * 128];
  __shared__ float fr[32 * 128];
  __shared__ float red[256];
  const int tid = threadIdx.x;
  float tot = 0.f;
  for (int idx = tid; idx < 4096; idx += 256) {
    const float v = fs[idx];
    f[idx] = v * (1.f / (float)T2_);
    tot += v;
  }
  red[tid] = tot;
  __syncthreads();
  for (int s = 128; s > 0; s >>= 1) {
    if (tid < s) red[tid] += red[tid + s];
    __syncthreads();
  }
  {
    const int bb = tid >> 3, og = tid & 7;
    float a[16];
#pragma unroll
    for (int j = 0; j < 16; ++j) a[j] = fcb[og * 16 + j];
    for (int hh = 0; hh < 128; ++hh) {
      const float fv = f[bb * 128 + hh];
#pragma unroll
      for (int j = 0; j < 16; ++j)
        a[j] = fmaf(fv, fcw[hh * 128 + og * 16 + j], a[j]);
    }
#pragma unroll
    for (int j = 0; j < 16; ++j) fr[bb * 128 + og * 16 + j] = fmaxf(a[j], 0.f);
  }
  __syncthreads();
  if (tid < 128) {
    const int bb = tid >> 2, cls = tid & 3;
    float a = ob[cls];
    for (int o = 0; o < 128; ++o) a = fmaf(fr[bb * 128 + o], ow[o * 4 + cls], a);
    out[bb * 4 + cls] = a;
  }
  if (tid == 0) out[128] = red[0] * (1.f / (4096.f * 1024.f));
}

// ---------------------------------------------------------------------------
extern "C" void kernel_launch(void* const* d_in, const int* in_sizes, int n_in,
                              void* d_out, int out_size, void* d_ws, size_t ws_size,
                              hipStream_t stream) {
  const float* X     = (const float*)d_in[0];
  const float* convw = (const float*)d_in[1];
  const float* convb = (const float*)d_in[2];
  const float* ln1s  = (const float*)d_in[3];
  const float* ln1b  = (const float*)d_in[4];
  const float* qw    = (const float*)d_in[5];
  const float* qb    = (const float*)d_in[6];
  const float* kw    = (const float*)d_in[7];
  const float* kb    = (const float*)d_in[8];
  const float* caw   = (const float*)d_in[9];
  const float* cab   = (const float*)d_in[10];
  const float* mixw  = (const float*)d_in[11];
  const float* mixb  = (const float*)d_in[12];
  const float* ln2s  = (const float*)d_in[13];
  const float* ln2b  = (const float*)d_in[14];
  const float* dl    = (const float*)d_in[15];
  const float* fcw   = (const float*)d_in[16];
  const float* fcb   = (const float*)d_in[17];
  const float* outw  = (const float*)d_in[18];
  const float* outb  = (const float*)d_in[19];

  float* ws  = (float*)d_ws;
  u16* Wth   = (u16*)(ws + OFF_WTH);
  u16* Wtl   = (u16*)(ws + OFF_WTL);
  float* xsp = ws + OFF_XSP;
  float* Aou = ws + OFF_A;
  float* Xm  = ws + OFF_XM;
  float* fs  = ws + OFF_A;   // reuse (A' dead after k3)

  dim3 g1(32, 32);
  k1_conv_ln<<<g1, 256, 0, stream>>>(X, convw, convb, ln1s, ln1b, xsp);
  k2_graph<<<32, 256, 0, stream>>>(xsp, qw, qb, kw, kb, caw, cab, Aou);
  k3_weff<<<1024, 256, 0, stream>>>(Aou, mixw, Wth, Wtl);
  k4_fused<<<512, 256, 0, stream>>>(X, convw, convb, ln1s, ln1b,
                                    Wth, Wtl, mixb, ln2s, ln2b, Xm);
  k5_lif<<<64, 64, 0, stream>>>(Xm, dl, fs);
  k6_head<<<1, 256, 0, stream>>>(fs, fcw, fcb, outw, outb, (float*)d_out);
}